// Round 4
// baseline (419.108 us; speedup 1.0000x reference)
//
#include <hip/hip_runtime.h>

using u16 = unsigned short;
using s16x8 = __attribute__((ext_vector_type(8))) short;
using f32x4 = __attribute__((ext_vector_type(4))) float;

__device__ __forceinline__ float bf2f(u16 u) {
  union { unsigned int i; float f; } c; c.i = ((unsigned int)u) << 16; return c.f;
}
__device__ __forceinline__ u16 f2bf(float f) {
  union { float f; unsigned int i; } c; c.f = f;
  unsigned int x = c.i;
  return (u16)((x + 0x7fffu + ((x >> 16) & 1u)) >> 16);
}

// ---------------------------------------------------------------------------
// Sentinel fill (ws_size guard diagnostic)
// ---------------------------------------------------------------------------
__global__ __launch_bounds__(256) void fill_kernel(float* out, int n) {
  int i = blockIdx.x * 256 + threadIdx.x;
  if (i < n) out[i] = 999.0f;
}

// ---------------------------------------------------------------------------
// Fused convert+transpose: fp32 in[R][C] -> bf16 out[C][R]
// ---------------------------------------------------------------------------
__global__ __launch_bounds__(256) void convT_kernel(
    const float* __restrict__ in, u16* __restrict__ out, int R, int C) {
  __shared__ u16 t[64][72];
  const int nbc = C >> 6;
  const int br = blockIdx.x / nbc, bc = blockIdx.x % nbc;
  const int tid = threadIdx.x;
  const int r4 = tid >> 4;          // 0..15
  const int c4 = (tid & 15) * 4;    // 0..60
  for (int i = 0; i < 4; i++) {
    int row = i * 16 + r4;
    float4 v = *(const float4*)(in + (size_t)(br * 64 + row) * C + bc * 64 + c4);
    t[row][c4 + 0] = f2bf(v.x); t[row][c4 + 1] = f2bf(v.y);
    t[row][c4 + 2] = f2bf(v.z); t[row][c4 + 3] = f2bf(v.w);
  }
  __syncthreads();
  for (int i = 0; i < 4; i++) {
    int row2 = i * 16 + r4;         // C-index
    ushort4 v;
    v.x = t[c4 + 0][row2]; v.y = t[c4 + 1][row2];
    v.z = t[c4 + 2][row2]; v.w = t[c4 + 3][row2];
    *(ushort4*)(out + (size_t)(bc * 64 + row2) * R + br * 64 + c4) = v;
  }
}

// ---------------------------------------------------------------------------
// LayerNorm: fp32 in -> bf16 out. Unbiased var (/1023), eps added to std.
// ---------------------------------------------------------------------------
__global__ __launch_bounds__(256) void ln_kernel(
    const float* __restrict__ x, u16* __restrict__ y,
    const float* __restrict__ alpha, const float* __restrict__ beta) {
  __shared__ float red[8];
  const int row = blockIdx.x;
  const int tid = threadIdx.x;
  float4 u = ((const float4*)(x + (size_t)row * 1024))[tid];
  float v0 = u.x, v1 = u.y, v2 = u.z, v3 = u.w;
  float s = v0 + v1 + v2 + v3;
  for (int off = 32; off; off >>= 1) s += __shfl_xor(s, off, 64);
  if ((tid & 63) == 0) red[tid >> 6] = s;
  __syncthreads();
  float mean = (red[0] + red[1] + red[2] + red[3]) * (1.f / 1024.f);
  v0 -= mean; v1 -= mean; v2 -= mean; v3 -= mean;
  float q = v0 * v0 + v1 * v1 + v2 * v2 + v3 * v3;
  for (int off = 32; off; off >>= 1) q += __shfl_xor(q, off, 64);
  if ((tid & 63) == 0) red[4 + (tid >> 6)] = q;
  __syncthreads();
  float var = (red[4] + red[5] + red[6] + red[7]) * (1.f / 1023.f);
  float inv = 1.f / (sqrtf(var) + 1e-6f);
  float a = alpha[0], b = beta[0];
  ushort4 o;
  o.x = f2bf(a * v0 * inv + b); o.y = f2bf(a * v1 * inv + b);
  o.z = f2bf(a * v2 * inv + b); o.w = f2bf(a * v3 * inv + b);
  ((ushort4*)(y + (size_t)row * 1024))[tid] = o;
}

// ---------------------------------------------------------------------------
// GEMM: C[M,N] = A[M,K](bf16) * Bt[N,K]^T(bf16) + bias(fp32) [+res(fp32)]
// EPI: 0 = bias -> bf16        1 = bias+relu -> bf16
//      2 = bias+res -> fp32    3 = bias -> bf16 V^T layout
//      4 = res only -> fp32 (no bias)
// 128x128 tile, BK=64, 4 waves (2x2), 16x16x32 bf16 MFMA, reg-staged LDS.
// ---------------------------------------------------------------------------
template<int EPI>
__global__ __launch_bounds__(256) void gemm_bt(
    const u16* __restrict__ A, const u16* __restrict__ Bt,
    const float* __restrict__ bias, const float* __restrict__ res,
    void* __restrict__ Cv, int M, int N, int K, int lda, int ldb, int ldc) {
  __shared__ u16 As[128 * 64];
  __shared__ u16 Bs[128 * 64];
  const int bn = blockIdx.x, bm = blockIdx.y;
  const int m0 = bm * 128, n0 = bn * 128;
  const int tid = threadIdx.x;
  const int w = tid >> 6, l = tid & 63;
  const int lr = l & 15, lg = l >> 4;
  const int wr = w >> 1, wc = w & 1;

  f32x4 acc[4][4] = {};

  for (int k0 = 0; k0 < K; k0 += 64) {
#pragma unroll
    for (int c = 0; c < 4; c++) {
      const int o = w * 4096 + c * 1024 + l * 16;      // linear LDS byte offset
      const int row = o >> 7;                          // tile row (128B rows)
      const int cb = o & 127;                          // byte col within row
      s16x8 va = *(const s16x8*)((const char*)A + ((size_t)(m0 + row) * lda + k0) * 2 + cb);
      s16x8 vb = *(const s16x8*)((const char*)Bt + ((size_t)(n0 + row) * ldb + k0) * 2 + cb);
      *(s16x8*)((char*)As + o) = va;
      *(s16x8*)((char*)Bs + o) = vb;
    }
    __syncthreads();
#pragma unroll
    for (int kk = 0; kk < 2; kk++) {
      const int kb = kk * 64 + lg * 16;                // byte col within row
      s16x8 a[4], b[4];
      for (int mi = 0; mi < 4; mi++) {
        int row = wr * 64 + mi * 16 + lr;
        a[mi] = *(const s16x8*)((const char*)As + ((row << 7) | kb));
      }
      for (int ni = 0; ni < 4; ni++) {
        int row = wc * 64 + ni * 16 + lr;
        b[ni] = *(const s16x8*)((const char*)Bs + ((row << 7) | kb));
      }
      for (int mi = 0; mi < 4; mi++)
        for (int ni = 0; ni < 4; ni++)
          acc[mi][ni] = __builtin_amdgcn_mfma_f32_16x16x32_bf16(
              a[mi], b[ni], acc[mi][ni], 0, 0, 0);
    }
    __syncthreads();
  }

  for (int mi = 0; mi < 4; mi++) {
    for (int ni = 0; ni < 4; ni++) {
      const int n = n0 + wc * 64 + ni * 16 + lr;
      const float bv = (EPI == 4) ? 0.f : bias[n];
      for (int r = 0; r < 4; r++) {
        const int m = m0 + wr * 64 + mi * 16 + lg * 4 + r;
        float v = acc[mi][ni][r] + bv;
        if (EPI == 1) v = v > 0.f ? v : 0.f;
        if (EPI == 2 || EPI == 4) {
          v += res[(size_t)m * ldc + n];
          ((float*)Cv)[(size_t)m * ldc + n] = v;
        } else if (EPI == 3) {
          // V^T layout: [B][n=h*64+dk][S]; b = m>>10, s = m&1023
          ((u16*)Cv)[(((size_t)(m >> 10)) * 1024 + n) * 1024 + (m & 1023)] = f2bf(v);
        } else {
          ((u16*)Cv)[(size_t)m * ldc + n] = f2bf(v);
        }
      }
    }
  }
}

// ---------------------------------------------------------------------------
// Flash attention: block = (qb, bh), 4 waves x 16 q-rows, KV tiles of 32.
// q,k: [B*S, 1024] bf16 (heads interleaved); vT: [B][1024][S] bf16
// ---------------------------------------------------------------------------
__global__ __launch_bounds__(256) void attn_kernel(
    const u16* __restrict__ q, const u16* __restrict__ k,
    const u16* __restrict__ vT, const int* __restrict__ mask,
    u16* __restrict__ ctx) {
  __shared__ u16 Pl[4][16][40];
  const int qb = blockIdx.x;          // 0..15
  const int bh = blockIdx.y;          // 0..63
  const int b = bh >> 4, h = bh & 15;
  const int tid = threadIdx.x;
  const int w = tid >> 6, l = tid & 63;
  const int lr = l & 15, lg = l >> 4;
  const int qrow0 = qb * 64 + w * 16;

  const u16* qp = q + ((size_t)(b * 1024 + qrow0 + lr)) * 1024 + h * 64 + lg * 8;
  const s16x8 aq0 = *(const s16x8*)qp;
  const s16x8 aq1 = *(const s16x8*)(qp + 32);

  float mrow[4], lrow[4];
  f32x4 acc[4] = {};
  for (int r = 0; r < 4; r++) { mrow[r] = -1e30f; lrow[r] = 0.f; }

  const u16* kbase = k + ((size_t)(b * 1024)) * 1024 + h * 64;
  const u16* vbase = vT + ((size_t)b) * 1024 * 1024 + ((size_t)(h * 64)) * 1024;

  for (int t0 = 0; t0 < 1024; t0 += 32) {
    float p[2][4];
    for (int sub = 0; sub < 2; sub++) {
      const int tc = t0 + sub * 16 + lr;
      const u16* kr = kbase + (size_t)tc * 1024 + lg * 8;
      s16x8 bk0 = *(const s16x8*)kr;
      s16x8 bk1 = *(const s16x8*)(kr + 32);
      f32x4 d = {};
      d = __builtin_amdgcn_mfma_f32_16x16x32_bf16(aq0, bk0, d, 0, 0, 0);
      d = __builtin_amdgcn_mfma_f32_16x16x32_bf16(aq1, bk1, d, 0, 0, 0);
      const int mv = mask[b * 1024 + tc];
      for (int r = 0; r < 4; r++) {
        float s = d[r] * 0.125f;
        p[sub][r] = (mv == 0) ? -1e9f : s;
      }
    }
    float tmax[4];
    for (int r = 0; r < 4; r++) tmax[r] = fmaxf(p[0][r], p[1][r]);
    for (int off = 1; off < 16; off <<= 1)
      for (int r = 0; r < 4; r++) tmax[r] = fmaxf(tmax[r], __shfl_xor(tmax[r], off, 64));
    float scl[4];
    for (int r = 0; r < 4; r++) {
      float mn = fmaxf(mrow[r], tmax[r]);
      scl[r] = __expf(mrow[r] - mn);
      mrow[r] = mn;
    }
    float ps[4];
    for (int r = 0; r < 4; r++) {
      p[0][r] = __expf(p[0][r] - mrow[r]);
      p[1][r] = __expf(p[1][r] - mrow[r]);
      ps[r] = p[0][r] + p[1][r];
    }
    for (int off = 1; off < 16; off <<= 1)
      for (int r = 0; r < 4; r++) ps[r] += __shfl_xor(ps[r], off, 64);
    for (int r = 0; r < 4; r++) lrow[r] = lrow[r] * scl[r] + ps[r];
    for (int d4 = 0; d4 < 4; d4++)
      for (int r = 0; r < 4; r++) acc[d4][r] *= scl[r];
    __syncthreads();
    for (int sub = 0; sub < 2; sub++)
      for (int r = 0; r < 4; r++)
        Pl[w][lg * 4 + r][sub * 16 + lr] = f2bf(p[sub][r]);
    __syncthreads();
    const s16x8 ap = *(const s16x8*)&Pl[w][lr][lg * 8];
    for (int d4 = 0; d4 < 4; d4++) {
      const u16* vr = vbase + (size_t)(d4 * 16 + lr) * 1024 + t0 + lg * 8;
      s16x8 bv = *(const s16x8*)vr;
      acc[d4] = __builtin_amdgcn_mfma_f32_16x16x32_bf16(ap, bv, acc[d4], 0, 0, 0);
    }
  }
  for (int d4 = 0; d4 < 4; d4++)
    for (int r = 0; r < 4; r++) {
      const int row = b * 1024 + qrow0 + lg * 4 + r;
      ctx[(size_t)row * 1024 + h * 64 + d4 * 16 + lr] = f2bf(acc[d4][r] / lrow[r]);
    }
}

// ---------------------------------------------------------------------------
// Workspace layout (56 MB peak; ws_size >= 64 MB proven in round 3):
//  [ 0.. 8) wqT,wkT,wvT,woT (bf16)   -> w1T after O-proj
//  [ 8..16) xn (bf16; ctx after QKV) -> w2T after O-proj
//  [16..24) qbuf (bf16)              -> xn2 after attention
//  [24..32) kbuf (bf16)              \__ hbuf (16 MB) after attention
//  [32..40) vT  (bf16)               /
//  [40..56) x1 (fp32)
// ---------------------------------------------------------------------------
extern "C" void kernel_launch(void* const* d_in, const int* in_sizes, int n_in,
                              void* d_out, int out_size, void* d_ws, size_t ws_size,
                              hipStream_t stream) {
  float* out = (float*)d_out;

  const size_t REQUIRED = (size_t)56 * 1024 * 1024;
  if (ws_size < REQUIRED) {
    fill_kernel<<<dim3((out_size + 255) / 256), 256, 0, stream>>>(out, out_size);
    return;
  }

  const float* x    = (const float*)d_in[0];
  const int*   mask = (const int*)d_in[1];
  const float* wq = (const float*)d_in[2];
  const float* bq = (const float*)d_in[3];
  const float* wk = (const float*)d_in[4];
  const float* bk = (const float*)d_in[5];
  const float* wv = (const float*)d_in[6];
  const float* bv = (const float*)d_in[7];
  const float* wo = (const float*)d_in[8];
  const float* bo = (const float*)d_in[9];
  const float* w1 = (const float*)d_in[10];
  const float* b1 = (const float*)d_in[11];
  const float* w2 = (const float*)d_in[12];
  const float* b2 = (const float*)d_in[13];
  const float* alpha1 = (const float*)d_in[14];
  const float* beta1  = (const float*)d_in[15];
  const float* alpha2 = (const float*)d_in[16];
  const float* beta2  = (const float*)d_in[17];

  char* W = (char*)d_ws;
  const size_t MB = 1024 * 1024;
  u16* wqT  = (u16*)(W + 0 * MB);
  u16* wkT  = (u16*)(W + 2 * MB);
  u16* wvT  = (u16*)(W + 4 * MB);
  u16* woT  = (u16*)(W + 6 * MB);
  u16* xn   = (u16*)(W + 8 * MB);
  u16* qbuf = (u16*)(W + 16 * MB);
  u16* kbuf = (u16*)(W + 24 * MB);
  u16* vT   = (u16*)(W + 32 * MB);
  float* x1 = (float*)(W + 40 * MB);
  u16* ctx  = xn;                   // reuse after QKV GEMMs
  u16* w1T  = (u16*)(W + 0 * MB);   // reuse weightT region after O-proj
  u16* w2T  = (u16*)(W + 8 * MB);   // reuse xn/ctx after O-proj
  u16* xn2  = (u16*)(W + 16 * MB);  // reuse qbuf after attention
  u16* hbuf = (u16*)(W + 24 * MB);  // reuse kbuf+vT after attention (16 MB)

  // fp32 -> bf16^T weight conversion
  convT_kernel<<<dim3(16 * 16), 256, 0, stream>>>(wq, wqT, 1024, 1024);
  convT_kernel<<<dim3(16 * 16), 256, 0, stream>>>(wk, wkT, 1024, 1024);
  convT_kernel<<<dim3(16 * 16), 256, 0, stream>>>(wv, wvT, 1024, 1024);
  convT_kernel<<<dim3(16 * 16), 256, 0, stream>>>(wo, woT, 1024, 1024);

  ln_kernel<<<dim3(4096), 256, 0, stream>>>(x, xn, alpha1, beta1);

  gemm_bt<0><<<dim3(8, 32), 256, 0, stream>>>(xn, wqT, bq, nullptr, qbuf, 4096, 1024, 1024, 1024, 1024, 1024);
  gemm_bt<0><<<dim3(8, 32), 256, 0, stream>>>(xn, wkT, bk, nullptr, kbuf, 4096, 1024, 1024, 1024, 1024, 1024);
  gemm_bt<3><<<dim3(8, 32), 256, 0, stream>>>(xn, wvT, bv, nullptr, vT,   4096, 1024, 1024, 1024, 1024, 1024);

  attn_kernel<<<dim3(16, 64), 256, 0, stream>>>(qbuf, kbuf, vT, mask, ctx);

  // O-proj + residual (fp32 res = x, fp32 out = x1)
  gemm_bt<2><<<dim3(8, 32), 256, 0, stream>>>(ctx, woT, bo, x, x1, 4096, 1024, 1024, 1024, 1024, 1024);

  // FFN weights now (regions freed above)
  convT_kernel<<<dim3(16 * 64), 256, 0, stream>>>(w1, w1T, 1024, 4096);
  convT_kernel<<<dim3(64 * 16), 256, 0, stream>>>(w2, w2T, 4096, 1024);

  ln_kernel<<<dim3(4096), 256, 0, stream>>>(x1, xn2, alpha2, beta2);

  // FFN in two halves (hbuf = 4096x2048 bf16, 16 MB)
  // half 0
  gemm_bt<1><<<dim3(16, 32), 256, 0, stream>>>(xn2, w1T, b1, nullptr, hbuf,
                                               4096, 2048, 1024, 1024, 1024, 2048);
  gemm_bt<2><<<dim3(8, 32), 256, 0, stream>>>(hbuf, w2T, b2, x1, out,
                                              4096, 1024, 2048, 2048, 4096, 1024);
  // half 1
  gemm_bt<1><<<dim3(16, 32), 256, 0, stream>>>(xn2, w1T + (size_t)2048 * 1024, b1 + 2048, nullptr, hbuf,
                                               4096, 2048, 1024, 1024, 1024, 2048);
  gemm_bt<4><<<dim3(8, 32), 256, 0, stream>>>(hbuf, w2T + 2048, nullptr, out, out,
                                              4096, 1024, 2048, 2048, 4096, 1024);
}

// Round 5
// 411.789 us; speedup vs baseline: 1.0178x; 1.0178x over previous
//
#include <hip/hip_runtime.h>

using u16 = unsigned short;
using s16x8 = __attribute__((ext_vector_type(8))) short;
using f32x4 = __attribute__((ext_vector_type(4))) float;

__device__ __forceinline__ float bf2f(u16 u) {
  union { unsigned int i; float f; } c; c.i = ((unsigned int)u) << 16; return c.f;
}
__device__ __forceinline__ u16 f2bf(float f) {
  union { float f; unsigned int i; } c; c.f = f;
  unsigned int x = c.i;
  return (u16)((x + 0x7fffu + ((x >> 16) & 1u)) >> 16);
}

#define GLOAD16(g, l) __builtin_amdgcn_global_load_lds(                         \
    (const __attribute__((address_space(1))) void*)(g),                          \
    (__attribute__((address_space(3))) void*)(l), 16, 0, 0)

// ---------------------------------------------------------------------------
// Sentinel fill (ws_size guard diagnostic)
// ---------------------------------------------------------------------------
__global__ __launch_bounds__(256) void fill_kernel(float* out, int n) {
  int i = blockIdx.x * 256 + threadIdx.x;
  if (i < n) out[i] = 999.0f;
}

// ---------------------------------------------------------------------------
// Fused convert+transpose: fp32 in[R][C] -> bf16 out[C][R]
// ---------------------------------------------------------------------------
__global__ __launch_bounds__(256) void convT_kernel(
    const float* __restrict__ in, u16* __restrict__ out, int R, int C) {
  __shared__ u16 t[64][72];
  const int nbc = C >> 6;
  const int br = blockIdx.x / nbc, bc = blockIdx.x % nbc;
  const int tid = threadIdx.x;
  const int r4 = tid >> 4;          // 0..15
  const int c4 = (tid & 15) * 4;    // 0..60
  for (int i = 0; i < 4; i++) {
    int row = i * 16 + r4;
    float4 v = *(const float4*)(in + (size_t)(br * 64 + row) * C + bc * 64 + c4);
    t[row][c4 + 0] = f2bf(v.x); t[row][c4 + 1] = f2bf(v.y);
    t[row][c4 + 2] = f2bf(v.z); t[row][c4 + 3] = f2bf(v.w);
  }
  __syncthreads();
  for (int i = 0; i < 4; i++) {
    int row2 = i * 16 + r4;         // C-index
    ushort4 v;
    v.x = t[c4 + 0][row2]; v.y = t[c4 + 1][row2];
    v.z = t[c4 + 2][row2]; v.w = t[c4 + 3][row2];
    *(ushort4*)(out + (size_t)(bc * 64 + row2) * R + br * 64 + c4) = v;
  }
}

// ---------------------------------------------------------------------------
// LayerNorm: fp32 in -> bf16 out. Unbiased var (/1023), eps added to std.
// ---------------------------------------------------------------------------
__global__ __launch_bounds__(256) void ln_kernel(
    const float* __restrict__ x, u16* __restrict__ y,
    const float* __restrict__ alpha, const float* __restrict__ beta) {
  __shared__ float red[8];
  const int row = blockIdx.x;
  const int tid = threadIdx.x;
  float4 u = ((const float4*)(x + (size_t)row * 1024))[tid];
  float v0 = u.x, v1 = u.y, v2 = u.z, v3 = u.w;
  float s = v0 + v1 + v2 + v3;
  for (int off = 32; off; off >>= 1) s += __shfl_xor(s, off, 64);
  if ((tid & 63) == 0) red[tid >> 6] = s;
  __syncthreads();
  float mean = (red[0] + red[1] + red[2] + red[3]) * (1.f / 1024.f);
  v0 -= mean; v1 -= mean; v2 -= mean; v3 -= mean;
  float q = v0 * v0 + v1 * v1 + v2 * v2 + v3 * v3;
  for (int off = 32; off; off >>= 1) q += __shfl_xor(q, off, 64);
  if ((tid & 63) == 0) red[4 + (tid >> 6)] = q;
  __syncthreads();
  float var = (red[4] + red[5] + red[6] + red[7]) * (1.f / 1023.f);
  float inv = 1.f / (sqrtf(var) + 1e-6f);
  float a = alpha[0], b = beta[0];
  ushort4 o;
  o.x = f2bf(a * v0 * inv + b); o.y = f2bf(a * v1 * inv + b);
  o.z = f2bf(a * v2 * inv + b); o.w = f2bf(a * v3 * inv + b);
  ((ushort4*)(y + (size_t)row * 1024))[tid] = o;
}

// ---------------------------------------------------------------------------
// GEMM: C[M,N] = A[M,K](bf16) * Bt[N,K]^T(bf16) + bias(fp32) [+res(fp32)]
// EPI: 0 = bias -> bf16        1 = bias+relu -> bf16
//      2 = bias+res -> fp32    3 = bias -> bf16 V^T layout
//      4 = res only -> fp32 (no bias)
// 128x128 tile, BK=64, 4 waves (2x2), 16x16x32 bf16 MFMA,
// m97-exact linear global_load_lds (width 16) staging.
// ---------------------------------------------------------------------------
template<int EPI>
__global__ __launch_bounds__(256) void gemm_bt(
    const u16* __restrict__ A, const u16* __restrict__ Bt,
    const float* __restrict__ bias, const float* __restrict__ res,
    void* __restrict__ Cv, int M, int N, int K, int lda, int ldb, int ldc) {
  __shared__ u16 As[128 * 64];
  __shared__ u16 Bs[128 * 64];
  const int bn = blockIdx.x, bm = blockIdx.y;
  const int m0 = bm * 128, n0 = bn * 128;
  const int tid = threadIdx.x;
  const int w = tid >> 6, l = tid & 63;
  const int lr = l & 15, lg = l >> 4;
  const int wr = w >> 1, wc = w & 1;

  f32x4 acc[4][4] = {};

  for (int k0 = 0; k0 < K; k0 += 64) {
#pragma unroll
    for (int c = 0; c < 4; c++) {
      const int o = w * 4096 + c * 1024 + l * 16;      // linear LDS byte offset
      const int row = o >> 7;                          // tile row (128B rows)
      const int cb = o & 127;                          // byte col within row
      GLOAD16((const char*)A + ((size_t)(m0 + row) * lda + k0) * 2 + cb,
              (char*)As + w * 4096 + c * 1024);
      GLOAD16((const char*)Bt + ((size_t)(n0 + row) * ldb + k0) * 2 + cb,
              (char*)Bs + w * 4096 + c * 1024);
    }
    __syncthreads();
#pragma unroll
    for (int kk = 0; kk < 2; kk++) {
      const int kb = kk * 64 + lg * 16;                // byte col within row
      s16x8 a[4], b[4];
      for (int mi = 0; mi < 4; mi++) {
        int row = wr * 64 + mi * 16 + lr;
        a[mi] = *(const s16x8*)((const char*)As + ((row << 7) | kb));
      }
      for (int ni = 0; ni < 4; ni++) {
        int row = wc * 64 + ni * 16 + lr;
        b[ni] = *(const s16x8*)((const char*)Bs + ((row << 7) | kb));
      }
      for (int mi = 0; mi < 4; mi++)
        for (int ni = 0; ni < 4; ni++)
          acc[mi][ni] = __builtin_amdgcn_mfma_f32_16x16x32_bf16(
              a[mi], b[ni], acc[mi][ni], 0, 0, 0);
    }
    __syncthreads();
  }

  for (int mi = 0; mi < 4; mi++) {
    for (int ni = 0; ni < 4; ni++) {
      const int n = n0 + wc * 64 + ni * 16 + lr;
      const float bv = (EPI == 4) ? 0.f : bias[n];
      for (int r = 0; r < 4; r++) {
        const int m = m0 + wr * 64 + mi * 16 + lg * 4 + r;
        float v = acc[mi][ni][r] + bv;
        if (EPI == 1) v = v > 0.f ? v : 0.f;
        if (EPI == 2 || EPI == 4) {
          v += res[(size_t)m * ldc + n];
          ((float*)Cv)[(size_t)m * ldc + n] = v;
        } else if (EPI == 3) {
          // V^T layout: [B][n=h*64+dk][S]; b = m>>10, s = m&1023
          ((u16*)Cv)[(((size_t)(m >> 10)) * 1024 + n) * 1024 + (m & 1023)] = f2bf(v);
        } else {
          ((u16*)Cv)[(size_t)m * ldc + n] = f2bf(v);
        }
      }
    }
  }
}

// ---------------------------------------------------------------------------
// Split-KV flash attention.
// block = (qb 0..63, bh 0..63): 16 q-rows; wave w owns KV range [w*256,(w+1)*256)
// No in-loop barriers (per-wave P tile); final LDS combine across 4 waves.
// q,k: [B*S, 1024] bf16; vT: [B][1024][S] bf16; ctx: [B*S,1024] bf16
// ---------------------------------------------------------------------------
__global__ __launch_bounds__(256) void attn_kernel(
    const u16* __restrict__ q, const u16* __restrict__ k,
    const u16* __restrict__ vT, const int* __restrict__ mask,
    u16* __restrict__ ctx) {
  __shared__ u16 Pl[4][16][40];
  __shared__ float accL[4][16][68];   // stride 68: 2-way (free) write conflicts
  __shared__ float mlL[4][16][2];
  const int qb = blockIdx.x;          // 0..63
  const int bh = blockIdx.y;          // 0..63
  const int b = bh >> 4, h = bh & 15;
  const int tid = threadIdx.x;
  const int w = tid >> 6, l = tid & 63;
  const int lr = l & 15, lg = l >> 4;
  const int qrow0 = qb * 16;

  const u16* qp = q + ((size_t)(b * 1024 + qrow0 + lr)) * 1024 + h * 64 + lg * 8;
  const s16x8 aq0 = *(const s16x8*)qp;
  const s16x8 aq1 = *(const s16x8*)(qp + 32);

  float mrow[4], lrow[4];
  f32x4 acc[4] = {};
  for (int r = 0; r < 4; r++) { mrow[r] = -1e30f; lrow[r] = 0.f; }

  const u16* kbase = k + ((size_t)(b * 1024)) * 1024 + h * 64;
  const u16* vbase = vT + ((size_t)b) * 1024 * 1024 + ((size_t)(h * 64)) * 1024;

  const int tbeg = w * 256, tend = tbeg + 256;
  for (int t0 = tbeg; t0 < tend; t0 += 32) {
    float p[2][4];
    for (int sub = 0; sub < 2; sub++) {
      const int tc = t0 + sub * 16 + lr;
      const u16* kr = kbase + (size_t)tc * 1024 + lg * 8;
      s16x8 bk0 = *(const s16x8*)kr;
      s16x8 bk1 = *(const s16x8*)(kr + 32);
      f32x4 d = {};
      d = __builtin_amdgcn_mfma_f32_16x16x32_bf16(aq0, bk0, d, 0, 0, 0);
      d = __builtin_amdgcn_mfma_f32_16x16x32_bf16(aq1, bk1, d, 0, 0, 0);
      const int mv = mask[b * 1024 + tc];
      for (int r = 0; r < 4; r++) {
        float s = d[r] * 0.125f;
        p[sub][r] = (mv == 0) ? -1e9f : s;
      }
    }
    float tmax[4];
    for (int r = 0; r < 4; r++) tmax[r] = fmaxf(p[0][r], p[1][r]);
    for (int off = 1; off < 16; off <<= 1)
      for (int r = 0; r < 4; r++) tmax[r] = fmaxf(tmax[r], __shfl_xor(tmax[r], off, 64));
    float scl[4];
    for (int r = 0; r < 4; r++) {
      float mn = fmaxf(mrow[r], tmax[r]);
      scl[r] = __expf(mrow[r] - mn);
      mrow[r] = mn;
    }
    float ps[4];
    for (int r = 0; r < 4; r++) {
      p[0][r] = __expf(p[0][r] - mrow[r]);
      p[1][r] = __expf(p[1][r] - mrow[r]);
      ps[r] = p[0][r] + p[1][r];
    }
    for (int off = 1; off < 16; off <<= 1)
      for (int r = 0; r < 4; r++) ps[r] += __shfl_xor(ps[r], off, 64);
    for (int r = 0; r < 4; r++) lrow[r] = lrow[r] * scl[r] + ps[r];
    for (int d4 = 0; d4 < 4; d4++)
      for (int r = 0; r < 4; r++) acc[d4][r] *= scl[r];
    // P -> per-wave LDS tile; wave-local fence only (rule #18)
    for (int sub = 0; sub < 2; sub++)
      for (int r = 0; r < 4; r++)
        Pl[w][lg * 4 + r][sub * 16 + lr] = f2bf(p[sub][r]);
    asm volatile("s_waitcnt lgkmcnt(0)" ::: "memory");
    __builtin_amdgcn_sched_barrier(0);
    const s16x8 ap = *(const s16x8*)&Pl[w][lr][lg * 8];
    for (int d4 = 0; d4 < 4; d4++) {
      const u16* vr = vbase + (size_t)(d4 * 16 + lr) * 1024 + t0 + lg * 8;
      s16x8 bv = *(const s16x8*)vr;
      acc[d4] = __builtin_amdgcn_mfma_f32_16x16x32_bf16(ap, bv, acc[d4], 0, 0, 0);
    }
  }

  // partials -> LDS
  for (int d4 = 0; d4 < 4; d4++)
    for (int r = 0; r < 4; r++)
      accL[w][lg * 4 + r][d4 * 16 + lr] = acc[d4][r];
  if (lr == 0)
    for (int r = 0; r < 4; r++) {
      mlL[w][lg * 4 + r][0] = mrow[r];
      mlL[w][lg * 4 + r][1] = lrow[r];
    }
  __syncthreads();

  // combine: thread -> (row = tid>>4, cols (tid&15)*4 .. +3)
  const int row = tid >> 4;
  const int c0 = (tid & 15) * 4;
  float mw[4], ew[4];
  float mstar = -1e30f;
  for (int ww = 0; ww < 4; ww++) { mw[ww] = mlL[ww][row][0]; mstar = fmaxf(mstar, mw[ww]); }
  float denom = 0.f;
  for (int ww = 0; ww < 4; ww++) { ew[ww] = __expf(mw[ww] - mstar); denom += mlL[ww][row][1] * ew[ww]; }
  const float rden = 1.f / denom;
  ushort4 o;
  u16* op = (u16*)&o;
  for (int j = 0; j < 4; j++) {
    float num = 0.f;
    for (int ww = 0; ww < 4; ww++) num += accL[ww][row][c0 + j] * ew[ww];
    op[j] = f2bf(num * rden);
  }
  *(ushort4*)(ctx + (size_t)(b * 1024 + qrow0 + row) * 1024 + h * 64 + c0) = o;
}

// ---------------------------------------------------------------------------
// Workspace layout (56 MB peak; ws_size >= 64 MB proven):
//  [ 0.. 8) wqT,wkT,wvT,woT (bf16)   -> w1T after O-proj
//  [ 8..16) xn (bf16; ctx after QKV) -> w2T after O-proj
//  [16..24) qbuf (bf16)              -> xn2 after attention
//  [24..32) kbuf (bf16)              \__ hbuf (16 MB) after attention
//  [32..40) vT  (bf16)               /
//  [40..56) x1 (fp32)
// ---------------------------------------------------------------------------
extern "C" void kernel_launch(void* const* d_in, const int* in_sizes, int n_in,
                              void* d_out, int out_size, void* d_ws, size_t ws_size,
                              hipStream_t stream) {
  float* out = (float*)d_out;

  const size_t REQUIRED = (size_t)56 * 1024 * 1024;
  if (ws_size < REQUIRED) {
    fill_kernel<<<dim3((out_size + 255) / 256), 256, 0, stream>>>(out, out_size);
    return;
  }

  const float* x    = (const float*)d_in[0];
  const int*   mask = (const int*)d_in[1];
  const float* wq = (const float*)d_in[2];
  const float* bq = (const float*)d_in[3];
  const float* wk = (const float*)d_in[4];
  const float* bk = (const float*)d_in[5];
  const float* wv = (const float*)d_in[6];
  const float* bv = (const float*)d_in[7];
  const float* wo = (const float*)d_in[8];
  const float* bo = (const float*)d_in[9];
  const float* w1 = (const float*)d_in[10];
  const float* b1 = (const float*)d_in[11];
  const float* w2 = (const float*)d_in[12];
  const float* b2 = (const float*)d_in[13];
  const float* alpha1 = (const float*)d_in[14];
  const float* beta1  = (const float*)d_in[15];
  const float* alpha2 = (const float*)d_in[16];
  const float* beta2  = (const float*)d_in[17];

  char* W = (char*)d_ws;
  const size_t MB = 1024 * 1024;
  u16* wqT  = (u16*)(W + 0 * MB);
  u16* wkT  = (u16*)(W + 2 * MB);
  u16* wvT  = (u16*)(W + 4 * MB);
  u16* woT  = (u16*)(W + 6 * MB);
  u16* xn   = (u16*)(W + 8 * MB);
  u16* qbuf = (u16*)(W + 16 * MB);
  u16* kbuf = (u16*)(W + 24 * MB);
  u16* vT   = (u16*)(W + 32 * MB);
  float* x1 = (float*)(W + 40 * MB);
  u16* ctx  = xn;                   // reuse after QKV GEMMs
  u16* w1T  = (u16*)(W + 0 * MB);   // reuse weightT region after O-proj
  u16* w2T  = (u16*)(W + 8 * MB);   // reuse xn/ctx after O-proj
  u16* xn2  = (u16*)(W + 16 * MB);  // reuse qbuf after attention
  u16* hbuf = (u16*)(W + 24 * MB);  // reuse kbuf+vT after attention (16 MB)

  // fp32 -> bf16^T weight conversion
  convT_kernel<<<dim3(16 * 16), 256, 0, stream>>>(wq, wqT, 1024, 1024);
  convT_kernel<<<dim3(16 * 16), 256, 0, stream>>>(wk, wkT, 1024, 1024);
  convT_kernel<<<dim3(16 * 16), 256, 0, stream>>>(wv, wvT, 1024, 1024);
  convT_kernel<<<dim3(16 * 16), 256, 0, stream>>>(wo, woT, 1024, 1024);

  ln_kernel<<<dim3(4096), 256, 0, stream>>>(x, xn, alpha1, beta1);

  gemm_bt<0><<<dim3(8, 32), 256, 0, stream>>>(xn, wqT, bq, nullptr, qbuf, 4096, 1024, 1024, 1024, 1024, 1024);
  gemm_bt<0><<<dim3(8, 32), 256, 0, stream>>>(xn, wkT, bk, nullptr, kbuf, 4096, 1024, 1024, 1024, 1024, 1024);
  gemm_bt<3><<<dim3(8, 32), 256, 0, stream>>>(xn, wvT, bv, nullptr, vT,   4096, 1024, 1024, 1024, 1024, 1024);

  attn_kernel<<<dim3(64, 64), 256, 0, stream>>>(qbuf, kbuf, vT, mask, ctx);

  // O-proj + residual (fp32 res = x, fp32 out = x1)
  gemm_bt<2><<<dim3(8, 32), 256, 0, stream>>>(ctx, woT, bo, x, x1, 4096, 1024, 1024, 1024, 1024, 1024);

  // FFN weights now (regions freed above)
  convT_kernel<<<dim3(16 * 64), 256, 0, stream>>>(w1, w1T, 1024, 4096);
  convT_kernel<<<dim3(64 * 16), 256, 0, stream>>>(w2, w2T, 4096, 1024);

  ln_kernel<<<dim3(4096), 256, 0, stream>>>(x1, xn2, alpha2, beta2);

  // FFN in two halves (hbuf = 4096x2048 bf16, 16 MB)
  // half 0
  gemm_bt<1><<<dim3(16, 32), 256, 0, stream>>>(xn2, w1T, b1, nullptr, hbuf,
                                               4096, 2048, 1024, 1024, 1024, 2048);
  gemm_bt<2><<<dim3(8, 32), 256, 0, stream>>>(hbuf, w2T, b2, x1, out,
                                              4096, 1024, 2048, 2048, 4096, 1024);
  // half 1
  gemm_bt<1><<<dim3(16, 32), 256, 0, stream>>>(xn2, w1T + (size_t)2048 * 1024, b1 + 2048, nullptr, hbuf,
                                               4096, 2048, 1024, 1024, 1024, 2048);
  gemm_bt<4><<<dim3(8, 32), 256, 0, stream>>>(hbuf, w2T + 2048, nullptr, out, out,
                                              4096, 1024, 2048, 2048, 4096, 1024);
}

// Round 6
// 400.251 us; speedup vs baseline: 1.0471x; 1.0288x over previous
//
#include <hip/hip_runtime.h>

using u16 = unsigned short;
using s16x8 = __attribute__((ext_vector_type(8))) short;
using f32x4 = __attribute__((ext_vector_type(4))) float;

__device__ __forceinline__ float bf2f(u16 u) {
  union { unsigned int i; float f; } c; c.i = ((unsigned int)u) << 16; return c.f;
}
__device__ __forceinline__ u16 f2bf(float f) {
  union { float f; unsigned int i; } c; c.f = f;
  unsigned int x = c.i;
  return (u16)((x + 0x7fffu + ((x >> 16) & 1u)) >> 16);
}

#define GLOAD16(g, l) __builtin_amdgcn_global_load_lds(                         \
    (const __attribute__((address_space(1))) void*)(g),                          \
    (__attribute__((address_space(3))) void*)(l), 16, 0, 0)

// ---------------------------------------------------------------------------
__global__ __launch_bounds__(256) void fill_kernel(float* out, int n) {
  int i = blockIdx.x * 256 + threadIdx.x;
  if (i < n) out[i] = 999.0f;
}

// ---------------------------------------------------------------------------
// Fused convert+transpose: fp32 in[R][C] -> bf16 out[C][R]
// ---------------------------------------------------------------------------
__global__ __launch_bounds__(256) void convT_kernel(
    const float* __restrict__ in, u16* __restrict__ out, int R, int C) {
  __shared__ u16 t[64][72];
  const int nbc = C >> 6;
  const int br = blockIdx.x / nbc, bc = blockIdx.x % nbc;
  const int tid = threadIdx.x;
  const int r4 = tid >> 4;          // 0..15
  const int c4 = (tid & 15) * 4;    // 0..60
  for (int i = 0; i < 4; i++) {
    int row = i * 16 + r4;
    float4 v = *(const float4*)(in + (size_t)(br * 64 + row) * C + bc * 64 + c4);
    t[row][c4 + 0] = f2bf(v.x); t[row][c4 + 1] = f2bf(v.y);
    t[row][c4 + 2] = f2bf(v.z); t[row][c4 + 3] = f2bf(v.w);
  }
  __syncthreads();
  for (int i = 0; i < 4; i++) {
    int row2 = i * 16 + r4;         // C-index
    ushort4 v;
    v.x = t[c4 + 0][row2]; v.y = t[c4 + 1][row2];
    v.z = t[c4 + 2][row2]; v.w = t[c4 + 3][row2];
    *(ushort4*)(out + (size_t)(bc * 64 + row2) * R + br * 64 + c4) = v;
  }
}

// ---------------------------------------------------------------------------
// LayerNorm: fp32 in -> bf16 out. Unbiased var (/1023), eps added to std.
// ---------------------------------------------------------------------------
__global__ __launch_bounds__(256) void ln_kernel(
    const float* __restrict__ x, u16* __restrict__ y,
    const float* __restrict__ alpha, const float* __restrict__ beta) {
  __shared__ float red[8];
  const int row = blockIdx.x;
  const int tid = threadIdx.x;
  float4 u = ((const float4*)(x + (size_t)row * 1024))[tid];
  float v0 = u.x, v1 = u.y, v2 = u.z, v3 = u.w;
  float s = v0 + v1 + v2 + v3;
  for (int off = 32; off; off >>= 1) s += __shfl_xor(s, off, 64);
  if ((tid & 63) == 0) red[tid >> 6] = s;
  __syncthreads();
  float mean = (red[0] + red[1] + red[2] + red[3]) * (1.f / 1024.f);
  v0 -= mean; v1 -= mean; v2 -= mean; v3 -= mean;
  float q = v0 * v0 + v1 * v1 + v2 * v2 + v3 * v3;
  for (int off = 32; off; off >>= 1) q += __shfl_xor(q, off, 64);
  if ((tid & 63) == 0) red[4 + (tid >> 6)] = q;
  __syncthreads();
  float var = (red[4] + red[5] + red[6] + red[7]) * (1.f / 1023.f);
  float inv = 1.f / (sqrtf(var) + 1e-6f);
  float a = alpha[0], b = beta[0];
  ushort4 o;
  o.x = f2bf(a * v0 * inv + b); o.y = f2bf(a * v1 * inv + b);
  o.z = f2bf(a * v2 * inv + b); o.w = f2bf(a * v3 * inv + b);
  ((ushort4*)(y + (size_t)row * 1024))[tid] = o;
}

// ---------------------------------------------------------------------------
// GEMM: C[M,N] = A[M,K](bf16) * Bt[N,K]^T(bf16) + bias(fp32) [+res(fp32)]
// EPI: 1 = bias+relu -> bf16   2 = bias+res -> fp32   4 = res only -> fp32
// 128x128 tile, BK=64, 4 waves (2x2), 16x16x32 bf16 MFMA,
// m97-exact linear global_load_lds (width 16) staging.
// ---------------------------------------------------------------------------
template<int EPI>
__global__ __launch_bounds__(256) void gemm_bt(
    const u16* __restrict__ A, const u16* __restrict__ Bt,
    const float* __restrict__ bias, const float* __restrict__ res,
    void* __restrict__ Cv, int M, int N, int K, int lda, int ldb, int ldc) {
  __shared__ u16 As[128 * 64];
  __shared__ u16 Bs[128 * 64];
  const int bn = blockIdx.x, bm = blockIdx.y;
  const int m0 = bm * 128, n0 = bn * 128;
  const int tid = threadIdx.x;
  const int w = tid >> 6, l = tid & 63;
  const int lr = l & 15, lg = l >> 4;
  const int wr = w >> 1, wc = w & 1;

  f32x4 acc[4][4] = {};

  for (int k0 = 0; k0 < K; k0 += 64) {
#pragma unroll
    for (int c = 0; c < 4; c++) {
      const int o = w * 4096 + c * 1024 + l * 16;      // linear LDS byte offset
      const int row = o >> 7;                          // tile row (128B rows)
      const int cb = o & 127;                          // byte col within row
      GLOAD16((const char*)A + ((size_t)(m0 + row) * lda + k0) * 2 + cb,
              (char*)As + w * 4096 + c * 1024);
      GLOAD16((const char*)Bt + ((size_t)(n0 + row) * ldb + k0) * 2 + cb,
              (char*)Bs + w * 4096 + c * 1024);
    }
    __syncthreads();
#pragma unroll
    for (int kk = 0; kk < 2; kk++) {
      const int kb = kk * 64 + lg * 16;                // byte col within row
      s16x8 a[4], b[4];
      for (int mi = 0; mi < 4; mi++) {
        int row = wr * 64 + mi * 16 + lr;
        a[mi] = *(const s16x8*)((const char*)As + ((row << 7) | kb));
      }
      for (int ni = 0; ni < 4; ni++) {
        int row = wc * 64 + ni * 16 + lr;
        b[ni] = *(const s16x8*)((const char*)Bs + ((row << 7) | kb));
      }
      for (int mi = 0; mi < 4; mi++)
        for (int ni = 0; ni < 4; ni++)
          acc[mi][ni] = __builtin_amdgcn_mfma_f32_16x16x32_bf16(
              a[mi], b[ni], acc[mi][ni], 0, 0, 0);
    }
    __syncthreads();
  }

  for (int mi = 0; mi < 4; mi++) {
    for (int ni = 0; ni < 4; ni++) {
      const int n = n0 + wc * 64 + ni * 16 + lr;
      const float bv = (EPI == 4) ? 0.f : bias[n];
      for (int r = 0; r < 4; r++) {
        const int m = m0 + wr * 64 + mi * 16 + lg * 4 + r;
        float v = acc[mi][ni][r] + bv;
        if (EPI == 1) v = v > 0.f ? v : 0.f;
        if (EPI == 2 || EPI == 4) {
          v += res[(size_t)m * ldc + n];
          ((float*)Cv)[(size_t)m * ldc + n] = v;
        } else {
          ((u16*)Cv)[(size_t)m * ldc + n] = f2bf(v);
        }
      }
    }
  }
}

// ---------------------------------------------------------------------------
// Fused QKV GEMM: A[4096,1024] x WT[3072,1024]^T; seg 0->qbuf, 1->kbuf,
// 2->vT (transposed [B][dk+h*64][S]). 768 blocks = 3/CU.
// ---------------------------------------------------------------------------
__global__ __launch_bounds__(256) void gemm_qkv(
    const u16* __restrict__ A, const u16* __restrict__ WT,
    const float* __restrict__ bq, const float* __restrict__ bk,
    const float* __restrict__ bv,
    u16* __restrict__ qb_, u16* __restrict__ kb_, u16* __restrict__ vT_) {
  __shared__ u16 As[128 * 64];
  __shared__ u16 Bs[128 * 64];
  const int bn = blockIdx.x, bm = blockIdx.y;
  const int m0 = bm * 128, n0 = bn * 128;
  const int tid = threadIdx.x;
  const int w = tid >> 6, l = tid & 63;
  const int lr = l & 15, lg = l >> 4;
  const int wr = w >> 1, wc = w & 1;

  f32x4 acc[4][4] = {};

  for (int k0 = 0; k0 < 1024; k0 += 64) {
#pragma unroll
    for (int c = 0; c < 4; c++) {
      const int o = w * 4096 + c * 1024 + l * 16;
      const int row = o >> 7;
      const int cb = o & 127;
      GLOAD16((const char*)A + ((size_t)(m0 + row) * 1024 + k0) * 2 + cb,
              (char*)As + w * 4096 + c * 1024);
      GLOAD16((const char*)WT + ((size_t)(n0 + row) * 1024 + k0) * 2 + cb,
              (char*)Bs + w * 4096 + c * 1024);
    }
    __syncthreads();
#pragma unroll
    for (int kk = 0; kk < 2; kk++) {
      const int kb = kk * 64 + lg * 16;
      s16x8 a[4], b[4];
      for (int mi = 0; mi < 4; mi++) {
        int row = wr * 64 + mi * 16 + lr;
        a[mi] = *(const s16x8*)((const char*)As + ((row << 7) | kb));
      }
      for (int ni = 0; ni < 4; ni++) {
        int row = wc * 64 + ni * 16 + lr;
        b[ni] = *(const s16x8*)((const char*)Bs + ((row << 7) | kb));
      }
      for (int mi = 0; mi < 4; mi++)
        for (int ni = 0; ni < 4; ni++)
          acc[mi][ni] = __builtin_amdgcn_mfma_f32_16x16x32_bf16(
              a[mi], b[ni], acc[mi][ni], 0, 0, 0);
    }
    __syncthreads();
  }

  const int seg = n0 >> 10;                    // uniform per block (128 | 1024)
  for (int mi = 0; mi < 4; mi++) {
    for (int ni = 0; ni < 4; ni++) {
      const int n = n0 + wc * 64 + ni * 16 + lr;
      const int nn = n & 1023;
      const float bias = seg == 0 ? bq[nn] : seg == 1 ? bk[nn] : bv[nn];
      for (int r = 0; r < 4; r++) {
        const int m = m0 + wr * 64 + mi * 16 + lg * 4 + r;
        const u16 ov = f2bf(acc[mi][ni][r] + bias);
        if (seg == 0)      qb_[(size_t)m * 1024 + nn] = ov;
        else if (seg == 1) kb_[(size_t)m * 1024 + nn] = ov;
        else               vT_[(((size_t)(m >> 10)) * 1024 + nn) * 1024 + (m & 1023)] = ov;
      }
    }
  }
}

// ---------------------------------------------------------------------------
// Split-KV flash attention, KVBLK=128.
// block = (qb 0..63, bh 0..63): 16 q-rows; wave w owns KV [w*256,(w+1)*256)
// (2 iterations of 128). Softmax trees amortized 4x vs KVBLK=32.
// ---------------------------------------------------------------------------
__global__ __launch_bounds__(256) void attn_kernel(
    const u16* __restrict__ q, const u16* __restrict__ k,
    const u16* __restrict__ vT, const int* __restrict__ mask,
    u16* __restrict__ ctx) {
  __shared__ union USm {
    u16 Pl[4][16][136];                        // 272B row stride (2-way free)
    struct { float accL[4][16][68]; float mlL[4][16][2]; } c;
  } sm;
  const int qb = blockIdx.x;          // 0..63
  const int bh = blockIdx.y;          // 0..63
  const int b = bh >> 4, h = bh & 15;
  const int tid = threadIdx.x;
  const int w = tid >> 6, l = tid & 63;
  const int lr = l & 15, lg = l >> 4;
  const int qrow0 = qb * 16;

  const u16* qp = q + ((size_t)(b * 1024 + qrow0 + lr)) * 1024 + h * 64 + lg * 8;
  const s16x8 aq0 = *(const s16x8*)qp;
  const s16x8 aq1 = *(const s16x8*)(qp + 32);

  float mrow[4], lrow[4];
  f32x4 acc[4] = {};
  for (int r = 0; r < 4; r++) { mrow[r] = -1e30f; lrow[r] = 0.f; }

  const u16* kbase = k + ((size_t)(b * 1024)) * 1024 + h * 64;
  const u16* vbase = vT + ((size_t)b) * 1024 * 1024 + ((size_t)(h * 64)) * 1024;

  const int tbeg = w * 256;
  for (int t0 = tbeg; t0 < tbeg + 256; t0 += 128) {
    float p[8][4];
#pragma unroll
    for (int sub = 0; sub < 8; sub++) {
      const int tc = t0 + sub * 16 + lr;
      const u16* kr = kbase + (size_t)tc * 1024 + lg * 8;
      s16x8 bk0 = *(const s16x8*)kr;
      s16x8 bk1 = *(const s16x8*)(kr + 32);
      f32x4 d = {};
      d = __builtin_amdgcn_mfma_f32_16x16x32_bf16(aq0, bk0, d, 0, 0, 0);
      d = __builtin_amdgcn_mfma_f32_16x16x32_bf16(aq1, bk1, d, 0, 0, 0);
      const int mv = mask[b * 1024 + tc];
      for (int r = 0; r < 4; r++) {
        float s = d[r] * 0.125f;
        p[sub][r] = (mv == 0) ? -1e9f : s;
      }
    }
    // row max: local over 8 subs, then 16-lane tree
    float tmax[4];
    for (int r = 0; r < 4; r++) {
      tmax[r] = p[0][r];
      for (int sub = 1; sub < 8; sub++) tmax[r] = fmaxf(tmax[r], p[sub][r]);
    }
    for (int off = 1; off < 16; off <<= 1)
      for (int r = 0; r < 4; r++) tmax[r] = fmaxf(tmax[r], __shfl_xor(tmax[r], off, 64));
    float scl[4];
    for (int r = 0; r < 4; r++) {
      float mn = fmaxf(mrow[r], tmax[r]);
      scl[r] = __expf(mrow[r] - mn);
      mrow[r] = mn;
    }
    float ps[4];
    for (int r = 0; r < 4; r++) {
      ps[r] = 0.f;
      for (int sub = 0; sub < 8; sub++) {
        p[sub][r] = __expf(p[sub][r] - mrow[r]);
        ps[r] += p[sub][r];
      }
    }
    for (int off = 1; off < 16; off <<= 1)
      for (int r = 0; r < 4; r++) ps[r] += __shfl_xor(ps[r], off, 64);
    for (int r = 0; r < 4; r++) lrow[r] = lrow[r] * scl[r] + ps[r];
    for (int d4 = 0; d4 < 4; d4++)
      for (int r = 0; r < 4; r++) acc[d4][r] *= scl[r];
    // P -> per-wave LDS tile; wave-local fence (rule #18)
#pragma unroll
    for (int sub = 0; sub < 8; sub++)
      for (int r = 0; r < 4; r++)
        sm.Pl[w][lg * 4 + r][sub * 16 + lr] = f2bf(p[sub][r]);
    asm volatile("s_waitcnt lgkmcnt(0)" ::: "memory");
    __builtin_amdgcn_sched_barrier(0);
#pragma unroll
    for (int kb2 = 0; kb2 < 4; kb2++) {
      const s16x8 ap = *(const s16x8*)&sm.Pl[w][lr][kb2 * 32 + lg * 8];
      for (int d4 = 0; d4 < 4; d4++) {
        const u16* vr = vbase + (size_t)(d4 * 16 + lr) * 1024 + t0 + kb2 * 32 + lg * 8;
        s16x8 bvv = *(const s16x8*)vr;
        acc[d4] = __builtin_amdgcn_mfma_f32_16x16x32_bf16(ap, bvv, acc[d4], 0, 0, 0);
      }
    }
  }

  // partials -> LDS (accL[w] aliases Pl[w]; DS ops are in-order per wave)
  for (int d4 = 0; d4 < 4; d4++)
    for (int r = 0; r < 4; r++)
      sm.c.accL[w][lg * 4 + r][d4 * 16 + lr] = acc[d4][r];
  if (lr == 0)
    for (int r = 0; r < 4; r++) {
      sm.c.mlL[w][lg * 4 + r][0] = mrow[r];
      sm.c.mlL[w][lg * 4 + r][1] = lrow[r];
    }
  __syncthreads();

  // combine: thread -> (row = tid>>4, cols (tid&15)*4 .. +3)
  const int row = tid >> 4;
  const int c0 = (tid & 15) * 4;
  float mw[4], ew[4];
  float mstar = -1e30f;
  for (int ww = 0; ww < 4; ww++) { mw[ww] = sm.c.mlL[ww][row][0]; mstar = fmaxf(mstar, mw[ww]); }
  float denom = 0.f;
  for (int ww = 0; ww < 4; ww++) { ew[ww] = __expf(mw[ww] - mstar); denom += sm.c.mlL[ww][row][1] * ew[ww]; }
  const float rden = 1.f / denom;
  ushort4 o;
  u16* op = (u16*)&o;
  for (int j = 0; j < 4; j++) {
    float num = 0.f;
    for (int ww = 0; ww < 4; ww++) num += sm.c.accL[ww][row][c0 + j] * ew[ww];
    op[j] = f2bf(num * rden);
  }
  *(ushort4*)(ctx + (size_t)(b * 1024 + qrow0 + row) * 1024 + h * 64 + c0) = o;
}

// ---------------------------------------------------------------------------
// Workspace layout (56 MB peak; ws_size >= 64 MB proven):
//  [ 0.. 6) wqT,wkT,wvT (contiguous => fused [3072][1024])  -> w1T after O-proj
//  [ 6.. 8) woT
//  [ 8..16) xn (bf16; ctx after QKV) -> w2T after O-proj
//  [16..24) qbuf (bf16)              -> xn2 after attention
//  [24..32) kbuf (bf16)              \__ hbuf (16 MB) after attention
//  [32..40) vT  (bf16)               /
//  [40..56) x1 (fp32)
// ---------------------------------------------------------------------------
extern "C" void kernel_launch(void* const* d_in, const int* in_sizes, int n_in,
                              void* d_out, int out_size, void* d_ws, size_t ws_size,
                              hipStream_t stream) {
  float* out = (float*)d_out;

  const size_t REQUIRED = (size_t)56 * 1024 * 1024;
  if (ws_size < REQUIRED) {
    fill_kernel<<<dim3((out_size + 255) / 256), 256, 0, stream>>>(out, out_size);
    return;
  }

  const float* x    = (const float*)d_in[0];
  const int*   mask = (const int*)d_in[1];
  const float* wq = (const float*)d_in[2];
  const float* bq = (const float*)d_in[3];
  const float* wk = (const float*)d_in[4];
  const float* bk = (const float*)d_in[5];
  const float* wv = (const float*)d_in[6];
  const float* bv = (const float*)d_in[7];
  const float* wo = (const float*)d_in[8];
  const float* bo = (const float*)d_in[9];
  const float* w1 = (const float*)d_in[10];
  const float* b1 = (const float*)d_in[11];
  const float* w2 = (const float*)d_in[12];
  const float* b2 = (const float*)d_in[13];
  const float* alpha1 = (const float*)d_in[14];
  const float* beta1  = (const float*)d_in[15];
  const float* alpha2 = (const float*)d_in[16];
  const float* beta2  = (const float*)d_in[17];

  char* W = (char*)d_ws;
  const size_t MB = 1024 * 1024;
  u16* wqT  = (u16*)(W + 0 * MB);
  u16* wkT  = (u16*)(W + 2 * MB);
  u16* wvT  = (u16*)(W + 4 * MB);
  u16* woT  = (u16*)(W + 6 * MB);
  u16* xn   = (u16*)(W + 8 * MB);
  u16* qbuf = (u16*)(W + 16 * MB);
  u16* kbuf = (u16*)(W + 24 * MB);
  u16* vT   = (u16*)(W + 32 * MB);
  float* x1 = (float*)(W + 40 * MB);
  u16* ctx  = xn;                   // reuse after QKV GEMM
  u16* w1T  = (u16*)(W + 0 * MB);   // reuse weightT region after O-proj
  u16* w2T  = (u16*)(W + 8 * MB);   // reuse xn/ctx after O-proj
  u16* xn2  = (u16*)(W + 16 * MB);  // reuse qbuf after attention
  u16* hbuf = (u16*)(W + 24 * MB);  // reuse kbuf+vT after attention (16 MB)

  // fp32 -> bf16^T weight conversion
  convT_kernel<<<dim3(16 * 16), 256, 0, stream>>>(wq, wqT, 1024, 1024);
  convT_kernel<<<dim3(16 * 16), 256, 0, stream>>>(wk, wkT, 1024, 1024);
  convT_kernel<<<dim3(16 * 16), 256, 0, stream>>>(wv, wvT, 1024, 1024);
  convT_kernel<<<dim3(16 * 16), 256, 0, stream>>>(wo, woT, 1024, 1024);

  ln_kernel<<<dim3(4096), 256, 0, stream>>>(x, xn, alpha1, beta1);

  // fused QKV: WT = wqT|wkT|wvT contiguous [3072][1024]
  gemm_qkv<<<dim3(24, 32), 256, 0, stream>>>(xn, wqT, bq, bk, bv, qbuf, kbuf, vT);

  attn_kernel<<<dim3(64, 64), 256, 0, stream>>>(qbuf, kbuf, vT, mask, ctx);

  // O-proj + residual (fp32 res = x, fp32 out = x1)
  gemm_bt<2><<<dim3(8, 32), 256, 0, stream>>>(ctx, woT, bo, x, x1, 4096, 1024, 1024, 1024, 1024, 1024);

  // FFN weights now (regions freed above)
  convT_kernel<<<dim3(16 * 64), 256, 0, stream>>>(w1, w1T, 1024, 4096);
  convT_kernel<<<dim3(64 * 16), 256, 0, stream>>>(w2, w2T, 4096, 1024);

  ln_kernel<<<dim3(4096), 256, 0, stream>>>(x1, xn2, alpha2, beta2);

  // FFN in two halves (hbuf = 4096x2048 bf16, 16 MB)
  gemm_bt<1><<<dim3(16, 32), 256, 0, stream>>>(xn2, w1T, b1, nullptr, hbuf,
                                               4096, 2048, 1024, 1024, 1024, 2048);
  gemm_bt<2><<<dim3(8, 32), 256, 0, stream>>>(hbuf, w2T, b2, x1, out,
                                              4096, 1024, 2048, 2048, 4096, 1024);
  gemm_bt<1><<<dim3(16, 32), 256, 0, stream>>>(xn2, w1T + (size_t)2048 * 1024, b1 + 2048, nullptr, hbuf,
                                               4096, 2048, 1024, 1024, 1024, 2048);
  gemm_bt<4><<<dim3(8, 32), 256, 0, stream>>>(hbuf, w2T + 2048, nullptr, out, out,
                                              4096, 1024, 2048, 2048, 4096, 1024);
}

// Round 7
// 348.571 us; speedup vs baseline: 1.2024x; 1.1483x over previous
//
#include <hip/hip_runtime.h>

using u16 = unsigned short;
using s16x8 = __attribute__((ext_vector_type(8))) short;
using f32x4 = __attribute__((ext_vector_type(4))) float;

__device__ __forceinline__ float bf2f(u16 u) {
  union { unsigned int i; float f; } c; c.i = ((unsigned int)u) << 16; return c.f;
}
__device__ __forceinline__ u16 f2bf(float f) {
  union { float f; unsigned int i; } c; c.f = f;
  unsigned int x = c.i;
  return (u16)((x + 0x7fffu + ((x >> 16) & 1u)) >> 16);
}

#define GLOAD16(g, l) __builtin_amdgcn_global_load_lds(                         \
    (const __attribute__((address_space(1))) void*)(g),                          \
    (__attribute__((address_space(3))) void*)(l), 16, 0, 0)

// ---------------------------------------------------------------------------
__global__ __launch_bounds__(256) void fill_kernel(float* out, int n) {
  int i = blockIdx.x * 256 + threadIdx.x;
  if (i < n) out[i] = 999.0f;
}

// ---------------------------------------------------------------------------
// Fused convert+transpose: fp32 in[R][C] -> bf16 out[C][R]
// ---------------------------------------------------------------------------
__global__ __launch_bounds__(256) void convT_kernel(
    const float* __restrict__ in, u16* __restrict__ out, int R, int C) {
  __shared__ u16 t[64][72];
  const int nbc = C >> 6;
  const int br = blockIdx.x / nbc, bc = blockIdx.x % nbc;
  const int tid = threadIdx.x;
  const int r4 = tid >> 4;          // 0..15
  const int c4 = (tid & 15) * 4;    // 0..60
  for (int i = 0; i < 4; i++) {
    int row = i * 16 + r4;
    float4 v = *(const float4*)(in + (size_t)(br * 64 + row) * C + bc * 64 + c4);
    t[row][c4 + 0] = f2bf(v.x); t[row][c4 + 1] = f2bf(v.y);
    t[row][c4 + 2] = f2bf(v.z); t[row][c4 + 3] = f2bf(v.w);
  }
  __syncthreads();
  for (int i = 0; i < 4; i++) {
    int row2 = i * 16 + r4;         // C-index
    ushort4 v;
    v.x = t[c4 + 0][row2]; v.y = t[c4 + 1][row2];
    v.z = t[c4 + 2][row2]; v.w = t[c4 + 3][row2];
    *(ushort4*)(out + (size_t)(bc * 64 + row2) * R + br * 64 + c4) = v;
  }
}

// ---------------------------------------------------------------------------
// LayerNorm: fp32 in -> bf16 out. Unbiased var (/1023), eps added to std.
// ---------------------------------------------------------------------------
__global__ __launch_bounds__(256) void ln_kernel(
    const float* __restrict__ x, u16* __restrict__ y,
    const float* __restrict__ alpha, const float* __restrict__ beta) {
  __shared__ float red[8];
  const int row = blockIdx.x;
  const int tid = threadIdx.x;
  float4 u = ((const float4*)(x + (size_t)row * 1024))[tid];
  float v0 = u.x, v1 = u.y, v2 = u.z, v3 = u.w;
  float s = v0 + v1 + v2 + v3;
  for (int off = 32; off; off >>= 1) s += __shfl_xor(s, off, 64);
  if ((tid & 63) == 0) red[tid >> 6] = s;
  __syncthreads();
  float mean = (red[0] + red[1] + red[2] + red[3]) * (1.f / 1024.f);
  v0 -= mean; v1 -= mean; v2 -= mean; v3 -= mean;
  float q = v0 * v0 + v1 * v1 + v2 * v2 + v3 * v3;
  for (int off = 32; off; off >>= 1) q += __shfl_xor(q, off, 64);
  if ((tid & 63) == 0) red[4 + (tid >> 6)] = q;
  __syncthreads();
  float var = (red[4] + red[5] + red[6] + red[7]) * (1.f / 1023.f);
  float inv = 1.f / (sqrtf(var) + 1e-6f);
  float a = alpha[0], b = beta[0];
  ushort4 o;
  o.x = f2bf(a * v0 * inv + b); o.y = f2bf(a * v1 * inv + b);
  o.z = f2bf(a * v2 * inv + b); o.w = f2bf(a * v3 * inv + b);
  ((ushort4*)(y + (size_t)row * 1024))[tid] = o;
}

// ---------------------------------------------------------------------------
// GEMM: C[M,N] = A[M,K](bf16) * Bt[N,K]^T(bf16) + bias(fp32) [+res(fp32)]
// EPI: 1 = bias+relu -> bf16   2 = bias+res -> fp32   4 = res only -> fp32
// 128x128 tile, BK=64, 4 waves (2x2), 16x16x32 bf16 MFMA,
// m97-exact linear global_load_lds (width 16) staging.
// ---------------------------------------------------------------------------
template<int EPI>
__global__ __launch_bounds__(256) void gemm_bt(
    const u16* __restrict__ A, const u16* __restrict__ Bt,
    const float* __restrict__ bias, const float* __restrict__ res,
    void* __restrict__ Cv, int M, int N, int K, int lda, int ldb, int ldc) {
  __shared__ u16 As[128 * 64];
  __shared__ u16 Bs[128 * 64];
  const int bn = blockIdx.x, bm = blockIdx.y;
  const int m0 = bm * 128, n0 = bn * 128;
  const int tid = threadIdx.x;
  const int w = tid >> 6, l = tid & 63;
  const int lr = l & 15, lg = l >> 4;
  const int wr = w >> 1, wc = w & 1;

  f32x4 acc[4][4] = {};

  for (int k0 = 0; k0 < K; k0 += 64) {
#pragma unroll
    for (int c = 0; c < 4; c++) {
      const int o = w * 4096 + c * 1024 + l * 16;      // linear LDS byte offset
      const int row = o >> 7;                          // tile row (128B rows)
      const int cb = o & 127;                          // byte col within row
      GLOAD16((const char*)A + ((size_t)(m0 + row) * lda + k0) * 2 + cb,
              (char*)As + w * 4096 + c * 1024);
      GLOAD16((const char*)Bt + ((size_t)(n0 + row) * ldb + k0) * 2 + cb,
              (char*)Bs + w * 4096 + c * 1024);
    }
    __syncthreads();
#pragma unroll
    for (int kk = 0; kk < 2; kk++) {
      const int kb = kk * 64 + lg * 16;                // byte col within row
      s16x8 a[4], b[4];
      for (int mi = 0; mi < 4; mi++) {
        int row = wr * 64 + mi * 16 + lr;
        a[mi] = *(const s16x8*)((const char*)As + ((row << 7) | kb));
      }
      for (int ni = 0; ni < 4; ni++) {
        int row = wc * 64 + ni * 16 + lr;
        b[ni] = *(const s16x8*)((const char*)Bs + ((row << 7) | kb));
      }
      for (int mi = 0; mi < 4; mi++)
        for (int ni = 0; ni < 4; ni++)
          acc[mi][ni] = __builtin_amdgcn_mfma_f32_16x16x32_bf16(
              a[mi], b[ni], acc[mi][ni], 0, 0, 0);
    }
    __syncthreads();
  }

  for (int mi = 0; mi < 4; mi++) {
    for (int ni = 0; ni < 4; ni++) {
      const int n = n0 + wc * 64 + ni * 16 + lr;
      const float bv = (EPI == 4) ? 0.f : bias[n];
      for (int r = 0; r < 4; r++) {
        const int m = m0 + wr * 64 + mi * 16 + lg * 4 + r;
        float v = acc[mi][ni][r] + bv;
        if (EPI == 1) v = v > 0.f ? v : 0.f;
        if (EPI == 2 || EPI == 4) {
          v += res[(size_t)m * ldc + n];
          ((float*)Cv)[(size_t)m * ldc + n] = v;
        } else {
          ((u16*)Cv)[(size_t)m * ldc + n] = f2bf(v);
        }
      }
    }
  }
}

// ---------------------------------------------------------------------------
// Fused QKV GEMM: A[4096,1024] x WT[3072,1024]^T; seg 0->qbuf, 1->kbuf,
// 2->vT (transposed [B][dk+h*64][S]). 768 blocks = 3/CU.
// ---------------------------------------------------------------------------
__global__ __launch_bounds__(256) void gemm_qkv(
    const u16* __restrict__ A, const u16* __restrict__ WT,
    const float* __restrict__ bq, const float* __restrict__ bk,
    const float* __restrict__ bv,
    u16* __restrict__ qb_, u16* __restrict__ kb_, u16* __restrict__ vT_) {
  __shared__ u16 As[128 * 64];
  __shared__ u16 Bs[128 * 64];
  const int bn = blockIdx.x, bm = blockIdx.y;
  const int m0 = bm * 128, n0 = bn * 128;
  const int tid = threadIdx.x;
  const int w = tid >> 6, l = tid & 63;
  const int lr = l & 15, lg = l >> 4;
  const int wr = w >> 1, wc = w & 1;

  f32x4 acc[4][4] = {};

  for (int k0 = 0; k0 < 1024; k0 += 64) {
#pragma unroll
    for (int c = 0; c < 4; c++) {
      const int o = w * 4096 + c * 1024 + l * 16;
      const int row = o >> 7;
      const int cb = o & 127;
      GLOAD16((const char*)A + ((size_t)(m0 + row) * 1024 + k0) * 2 + cb,
              (char*)As + w * 4096 + c * 1024);
      GLOAD16((const char*)WT + ((size_t)(n0 + row) * 1024 + k0) * 2 + cb,
              (char*)Bs + w * 4096 + c * 1024);
    }
    __syncthreads();
#pragma unroll
    for (int kk = 0; kk < 2; kk++) {
      const int kb = kk * 64 + lg * 16;
      s16x8 a[4], b[4];
      for (int mi = 0; mi < 4; mi++) {
        int row = wr * 64 + mi * 16 + lr;
        a[mi] = *(const s16x8*)((const char*)As + ((row << 7) | kb));
      }
      for (int ni = 0; ni < 4; ni++) {
        int row = wc * 64 + ni * 16 + lr;
        b[ni] = *(const s16x8*)((const char*)Bs + ((row << 7) | kb));
      }
      for (int mi = 0; mi < 4; mi++)
        for (int ni = 0; ni < 4; ni++)
          acc[mi][ni] = __builtin_amdgcn_mfma_f32_16x16x32_bf16(
              a[mi], b[ni], acc[mi][ni], 0, 0, 0);
    }
    __syncthreads();
  }

  const int seg = n0 >> 10;                    // uniform per block
  for (int mi = 0; mi < 4; mi++) {
    for (int ni = 0; ni < 4; ni++) {
      const int n = n0 + wc * 64 + ni * 16 + lr;
      const int nn = n & 1023;
      const float bias = seg == 0 ? bq[nn] : seg == 1 ? bk[nn] : bv[nn];
      for (int r = 0; r < 4; r++) {
        const int m = m0 + wr * 64 + mi * 16 + lg * 4 + r;
        const u16 ov = f2bf(acc[mi][ni][r] + bias);
        if (seg == 0)      qb_[(size_t)m * 1024 + nn] = ov;
        else if (seg == 1) kb_[(size_t)m * 1024 + nn] = ov;
        else               vT_[(((size_t)(m >> 10)) * 1024 + nn) * 1024 + (m & 1023)] = ov;
      }
    }
  }
}

// ---------------------------------------------------------------------------
// Flash attention, LDS-staged KV (double-buffered, XOR-swizzled).
// block = (qt 0..15, bh 0..63): 64 q-rows (4 waves x 16); sweep all 1024 KV
// in KVBLK=64 tiles shared by all waves via global_load_lds.
// q,k: [B*S,1024] bf16; vT: [B][1024][S] bf16; ctx: [B*S,1024] bf16
// ---------------------------------------------------------------------------
__global__ __launch_bounds__(256) void attn_kernel(
    const u16* __restrict__ q, const u16* __restrict__ k,
    const u16* __restrict__ vT, const int* __restrict__ mask,
    u16* __restrict__ ctx) {
  __shared__ u16 Ks[2][64 * 64];   // [kv][d] rows 128B, XOR-swizzled
  __shared__ u16 Vs[2][64 * 64];   // [d][kv] rows 128B, XOR-swizzled
  __shared__ u16 Pl[4][16][72];    // per-wave P tile (144B rows)
  const int qt = blockIdx.x;          // 0..15
  const int bh = blockIdx.y;          // 0..63
  const int b = bh >> 4, h = bh & 15;
  const int tid = threadIdx.x;
  const int w = tid >> 6, l = tid & 63;
  const int lr = l & 15, lg = l >> 4;
  const int qrow0 = qt * 64 + w * 16;

  const u16* qp = q + ((size_t)(b * 1024 + qrow0 + lr)) * 1024 + h * 64 + lg * 8;
  const s16x8 aq0 = *(const s16x8*)qp;
  const s16x8 aq1 = *(const s16x8*)(qp + 32);

  float mrow[4], lrow[4];
  f32x4 acc[4] = {};
  for (int r = 0; r < 4; r++) { mrow[r] = -1e30f; lrow[r] = 0.f; }

  const char* kby = (const char*)(k + ((size_t)(b * 1024)) * 1024 + h * 64);
  const char* vby = (const char*)(vT + ((size_t)b) * 1024 * 1024 + ((size_t)(h * 64)) * 1024);
  const int* mbase = mask + b * 1024;

  // staging: tile 8KB = 2 passes x 256 threads x 16B. Linear LDS dest
  // (wave-uniform base; HW adds lane*16); global source pre-swizzled (#21).
  const int o0 = tid * 16;                       // pass 0 linear byte offset
#define STAGE_KV(bufi, t0_)                                                     \
  {                                                                             \
    _Pragma("unroll")                                                           \
    for (int c = 0; c < 2; c++) {                                               \
      const int o = c * 4096 + o0;                                              \
      const int row = o >> 7;                                                   \
      const int cb = (o & 127) ^ ((row & 7) << 4);                              \
      GLOAD16(kby + (size_t)(t0_ + row) * 2048 + cb,                            \
              (char*)Ks + (bufi) * 8192 + c * 4096 + w * 1024);                 \
      GLOAD16(vby + (size_t)row * 2048 + (size_t)(t0_) * 2 + cb,                \
              (char*)Vs + (bufi) * 8192 + c * 4096 + w * 1024);                 \
    }                                                                           \
  }

  STAGE_KV(0, 0);
  __syncthreads();

  int buf = 0;
  for (int it = 0; it < 16; ++it) {
    const int t0 = it * 64;
    if (it < 15) STAGE_KV(buf ^ 1, t0 + 64);

    // ---- QK^T over 64 kv rows (4 subs of 16) ----
    float p[4][4];
#pragma unroll
    for (int sub = 0; sub < 4; sub++) {
      const int krow = sub * 16 + lr;
      const int sw = (krow & 7) << 4;
      const char* kp = (const char*)Ks + buf * 8192 + (krow << 7);
      s16x8 bk0 = *(const s16x8*)(kp + ((lg * 16) ^ sw));
      s16x8 bk1 = *(const s16x8*)(kp + ((lg * 16 + 64) ^ sw));
      f32x4 d = {};
      d = __builtin_amdgcn_mfma_f32_16x16x32_bf16(aq0, bk0, d, 0, 0, 0);
      d = __builtin_amdgcn_mfma_f32_16x16x32_bf16(aq1, bk1, d, 0, 0, 0);
      const int mv = mbase[t0 + krow];
      for (int r = 0; r < 4; r++) {
        float s = d[r] * 0.125f;
        p[sub][r] = (mv == 0) ? -1e9f : s;
      }
    }
    // ---- online softmax ----
    float tmax[4];
    for (int r = 0; r < 4; r++) {
      tmax[r] = fmaxf(fmaxf(p[0][r], p[1][r]), fmaxf(p[2][r], p[3][r]));
    }
    for (int off = 1; off < 16; off <<= 1)
      for (int r = 0; r < 4; r++) tmax[r] = fmaxf(tmax[r], __shfl_xor(tmax[r], off, 64));
    float scl[4];
    for (int r = 0; r < 4; r++) {
      float mn = fmaxf(mrow[r], tmax[r]);
      scl[r] = __expf(mrow[r] - mn);
      mrow[r] = mn;
    }
    float ps[4];
    for (int r = 0; r < 4; r++) {
      ps[r] = 0.f;
      for (int sub = 0; sub < 4; sub++) {
        p[sub][r] = __expf(p[sub][r] - mrow[r]);
        ps[r] += p[sub][r];
      }
    }
    for (int off = 1; off < 16; off <<= 1)
      for (int r = 0; r < 4; r++) ps[r] += __shfl_xor(ps[r], off, 64);
    for (int r = 0; r < 4; r++) lrow[r] = lrow[r] * scl[r] + ps[r];
    for (int d4 = 0; d4 < 4; d4++)
      for (int r = 0; r < 4; r++) acc[d4][r] *= scl[r];
    // ---- P -> per-wave LDS; wave-local fence (rule #18) ----
#pragma unroll
    for (int sub = 0; sub < 4; sub++)
      for (int r = 0; r < 4; r++)
        Pl[w][lg * 4 + r][sub * 16 + lr] = f2bf(p[sub][r]);
    asm volatile("s_waitcnt lgkmcnt(0)" ::: "memory");
    __builtin_amdgcn_sched_barrier(0);
    // ---- PV: acc[q][d] += P[q][kv] * V^T[d][kv] ----
#pragma unroll
    for (int kb2 = 0; kb2 < 2; kb2++) {
      const s16x8 ap = *(const s16x8*)&Pl[w][lr][kb2 * 32 + lg * 8];
      for (int d4 = 0; d4 < 4; d4++) {
        const int vrow = d4 * 16 + lr;
        const char* vp = (const char*)Vs + buf * 8192 + (vrow << 7);
        s16x8 bvv = *(const s16x8*)(vp + ((kb2 * 64 + lg * 16) ^ ((vrow & 7) << 4)));
        acc[d4] = __builtin_amdgcn_mfma_f32_16x16x32_bf16(ap, bvv, acc[d4], 0, 0, 0);
      }
    }
    __syncthreads();
    buf ^= 1;
  }

  for (int d4 = 0; d4 < 4; d4++)
    for (int r = 0; r < 4; r++) {
      const int row = b * 1024 + qrow0 + lg * 4 + r;
      ctx[(size_t)row * 1024 + h * 64 + d4 * 16 + lr] = f2bf(acc[d4][r] / lrow[r]);
    }
#undef STAGE_KV
}

// ---------------------------------------------------------------------------
// Workspace layout (56 MB peak; ws_size >= 56 MB guarded):
//  [ 0.. 6) wqT,wkT,wvT (contiguous => fused [3072][1024])  -> w1T after O-proj
//  [ 6.. 8) woT
//  [ 8..16) xn (bf16; ctx after QKV) -> w2T after O-proj
//  [16..24) qbuf (bf16)              -> xn2 after attention
//  [24..32) kbuf (bf16)              \__ hbuf (16 MB) after attention
//  [32..40) vT  (bf16)               /
//  [40..56) x1 (fp32)
// ---------------------------------------------------------------------------
extern "C" void kernel_launch(void* const* d_in, const int* in_sizes, int n_in,
                              void* d_out, int out_size, void* d_ws, size_t ws_size,
                              hipStream_t stream) {
  float* out = (float*)d_out;

  const size_t REQUIRED = (size_t)56 * 1024 * 1024;
  if (ws_size < REQUIRED) {
    fill_kernel<<<dim3((out_size + 255) / 256), 256, 0, stream>>>(out, out_size);
    return;
  }

  const float* x    = (const float*)d_in[0];
  const int*   mask = (const int*)d_in[1];
  const float* wq = (const float*)d_in[2];
  const float* bq = (const float*)d_in[3];
  const float* wk = (const float*)d_in[4];
  const float* bk = (const float*)d_in[5];
  const float* wv = (const float*)d_in[6];
  const float* bv = (const float*)d_in[7];
  const float* wo = (const float*)d_in[8];
  const float* bo = (const float*)d_in[9];
  const float* w1 = (const float*)d_in[10];
  const float* b1 = (const float*)d_in[11];
  const float* w2 = (const float*)d_in[12];
  const float* b2 = (const float*)d_in[13];
  const float* alpha1 = (const float*)d_in[14];
  const float* beta1  = (const float*)d_in[15];
  const float* alpha2 = (const float*)d_in[16];
  const float* beta2  = (const float*)d_in[17];

  char* W = (char*)d_ws;
  const size_t MB = 1024 * 1024;
  u16* wqT  = (u16*)(W + 0 * MB);
  u16* wkT  = (u16*)(W + 2 * MB);
  u16* wvT  = (u16*)(W + 4 * MB);
  u16* woT  = (u16*)(W + 6 * MB);
  u16* xn   = (u16*)(W + 8 * MB);
  u16* qbuf = (u16*)(W + 16 * MB);
  u16* kbuf = (u16*)(W + 24 * MB);
  u16* vT   = (u16*)(W + 32 * MB);
  float* x1 = (float*)(W + 40 * MB);
  u16* ctx  = xn;                   // reuse after QKV GEMM
  u16* w1T  = (u16*)(W + 0 * MB);   // reuse weightT region after O-proj
  u16* w2T  = (u16*)(W + 8 * MB);   // reuse xn/ctx after O-proj
  u16* xn2  = (u16*)(W + 16 * MB);  // reuse qbuf after attention
  u16* hbuf = (u16*)(W + 24 * MB);  // reuse kbuf+vT after attention (16 MB)

  // fp32 -> bf16^T weight conversion
  convT_kernel<<<dim3(16 * 16), 256, 0, stream>>>(wq, wqT, 1024, 1024);
  convT_kernel<<<dim3(16 * 16), 256, 0, stream>>>(wk, wkT, 1024, 1024);
  convT_kernel<<<dim3(16 * 16), 256, 0, stream>>>(wv, wvT, 1024, 1024);
  convT_kernel<<<dim3(16 * 16), 256, 0, stream>>>(wo, woT, 1024, 1024);

  ln_kernel<<<dim3(4096), 256, 0, stream>>>(x, xn, alpha1, beta1);

  // fused QKV: WT = wqT|wkT|wvT contiguous [3072][1024]
  gemm_qkv<<<dim3(24, 32), 256, 0, stream>>>(xn, wqT, bq, bk, bv, qbuf, kbuf, vT);

  attn_kernel<<<dim3(16, 64), 256, 0, stream>>>(qbuf, kbuf, vT, mask, ctx);

  // O-proj + residual (fp32 res = x, fp32 out = x1)
  gemm_bt<2><<<dim3(8, 32), 256, 0, stream>>>(ctx, woT, bo, x, x1, 4096, 1024, 1024, 1024, 1024, 1024);

  // FFN weights now (regions freed above)
  convT_kernel<<<dim3(16 * 64), 256, 0, stream>>>(w1, w1T, 1024, 4096);
  convT_kernel<<<dim3(64 * 16), 256, 0, stream>>>(w2, w2T, 4096, 1024);

  ln_kernel<<<dim3(4096), 256, 0, stream>>>(x1, xn2, alpha2, beta2);

  // FFN in two halves (hbuf = 4096x2048 bf16, 16 MB)
  gemm_bt<1><<<dim3(16, 32), 256, 0, stream>>>(xn2, w1T, b1, nullptr, hbuf,
                                               4096, 2048, 1024, 1024, 1024, 2048);
  gemm_bt<2><<<dim3(8, 32), 256, 0, stream>>>(hbuf, w2T, b2, x1, out,
                                              4096, 1024, 2048, 2048, 4096, 1024);
  gemm_bt<1><<<dim3(16, 32), 256, 0, stream>>>(xn2, w1T + (size_t)2048 * 1024, b1 + 2048, nullptr, hbuf,
                                               4096, 2048, 1024, 1024, 1024, 2048);
  gemm_bt<4><<<dim3(8, 32), 256, 0, stream>>>(hbuf, w2T + 2048, nullptr, out, out,
                                              4096, 1024, 2048, 2048, 4096, 1024);
}

// Round 8
// 325.136 us; speedup vs baseline: 1.2890x; 1.0721x over previous
//
#include <hip/hip_runtime.h>

using u16 = unsigned short;
using s16x8 = __attribute__((ext_vector_type(8))) short;
using f32x4 = __attribute__((ext_vector_type(4))) float;

__device__ __forceinline__ float bf2f(u16 u) {
  union { unsigned int i; float f; } c; c.i = ((unsigned int)u) << 16; return c.f;
}
__device__ __forceinline__ u16 f2bf(float f) {
  union { float f; unsigned int i; } c; c.f = f;
  unsigned int x = c.i;
  return (u16)((x + 0x7fffu + ((x >> 16) & 1u)) >> 16);
}

#define GLOAD16(g, l) __builtin_amdgcn_global_load_lds(                         \
    (const __attribute__((address_space(1))) void*)(g),                          \
    (__attribute__((address_space(3))) void*)(l), 16, 0, 0)

// ---------------------------------------------------------------------------
__global__ __launch_bounds__(256) void fill_kernel(float* out, int n) {
  int i = blockIdx.x * 256 + threadIdx.x;
  if (i < n) out[i] = 999.0f;
}

// ---------------------------------------------------------------------------
// Fused convert+transpose: fp32 in[R][C] -> bf16 out[C][R]
// ---------------------------------------------------------------------------
__global__ __launch_bounds__(256) void convT_kernel(
    const float* __restrict__ in, u16* __restrict__ out, int R, int C) {
  __shared__ u16 t[64][72];
  const int nbc = C >> 6;
  const int br = blockIdx.x / nbc, bc = blockIdx.x % nbc;
  const int tid = threadIdx.x;
  const int r4 = tid >> 4;          // 0..15
  const int c4 = (tid & 15) * 4;    // 0..60
  for (int i = 0; i < 4; i++) {
    int row = i * 16 + r4;
    float4 v = *(const float4*)(in + (size_t)(br * 64 + row) * C + bc * 64 + c4);
    t[row][c4 + 0] = f2bf(v.x); t[row][c4 + 1] = f2bf(v.y);
    t[row][c4 + 2] = f2bf(v.z); t[row][c4 + 3] = f2bf(v.w);
  }
  __syncthreads();
  for (int i = 0; i < 4; i++) {
    int row2 = i * 16 + r4;         // C-index
    ushort4 v;
    v.x = t[c4 + 0][row2]; v.y = t[c4 + 1][row2];
    v.z = t[c4 + 2][row2]; v.w = t[c4 + 3][row2];
    *(ushort4*)(out + (size_t)(bc * 64 + row2) * R + br * 64 + c4) = v;
  }
}

// ---------------------------------------------------------------------------
// LayerNorm (unbiased var /1023, eps on std): fp32 or bf16 in -> bf16 out.
// ---------------------------------------------------------------------------
__global__ __launch_bounds__(256) void ln_kernel(
    const float* __restrict__ x, u16* __restrict__ y,
    const float* __restrict__ alpha, const float* __restrict__ beta) {
  __shared__ float red[8];
  const int row = blockIdx.x;
  const int tid = threadIdx.x;
  float4 u = ((const float4*)(x + (size_t)row * 1024))[tid];
  float v0 = u.x, v1 = u.y, v2 = u.z, v3 = u.w;
  float s = v0 + v1 + v2 + v3;
  for (int off = 32; off; off >>= 1) s += __shfl_xor(s, off, 64);
  if ((tid & 63) == 0) red[tid >> 6] = s;
  __syncthreads();
  float mean = (red[0] + red[1] + red[2] + red[3]) * (1.f / 1024.f);
  v0 -= mean; v1 -= mean; v2 -= mean; v3 -= mean;
  float q = v0 * v0 + v1 * v1 + v2 * v2 + v3 * v3;
  for (int off = 32; off; off >>= 1) q += __shfl_xor(q, off, 64);
  if ((tid & 63) == 0) red[4 + (tid >> 6)] = q;
  __syncthreads();
  float var = (red[4] + red[5] + red[6] + red[7]) * (1.f / 1023.f);
  float inv = 1.f / (sqrtf(var) + 1e-6f);
  float a = alpha[0], b = beta[0];
  ushort4 o;
  o.x = f2bf(a * v0 * inv + b); o.y = f2bf(a * v1 * inv + b);
  o.z = f2bf(a * v2 * inv + b); o.w = f2bf(a * v3 * inv + b);
  ((ushort4*)(y + (size_t)row * 1024))[tid] = o;
}

__global__ __launch_bounds__(256) void ln_bf16_kernel(
    const u16* __restrict__ x, u16* __restrict__ y,
    const float* __restrict__ alpha, const float* __restrict__ beta) {
  __shared__ float red[8];
  const int row = blockIdx.x;
  const int tid = threadIdx.x;
  ushort4 u = ((const ushort4*)(x + (size_t)row * 1024))[tid];
  float v0 = bf2f(u.x), v1 = bf2f(u.y), v2 = bf2f(u.z), v3 = bf2f(u.w);
  float s = v0 + v1 + v2 + v3;
  for (int off = 32; off; off >>= 1) s += __shfl_xor(s, off, 64);
  if ((tid & 63) == 0) red[tid >> 6] = s;
  __syncthreads();
  float mean = (red[0] + red[1] + red[2] + red[3]) * (1.f / 1024.f);
  v0 -= mean; v1 -= mean; v2 -= mean; v3 -= mean;
  float q = v0 * v0 + v1 * v1 + v2 * v2 + v3 * v3;
  for (int off = 32; off; off >>= 1) q += __shfl_xor(q, off, 64);
  if ((tid & 63) == 0) red[4 + (tid >> 6)] = q;
  __syncthreads();
  float var = (red[4] + red[5] + red[6] + red[7]) * (1.f / 1023.f);
  float inv = 1.f / (sqrtf(var) + 1e-6f);
  float a = alpha[0], b = beta[0];
  ushort4 o;
  o.x = f2bf(a * v0 * inv + b); o.y = f2bf(a * v1 * inv + b);
  o.z = f2bf(a * v2 * inv + b); o.w = f2bf(a * v3 * inv + b);
  ((ushort4*)(y + (size_t)row * 1024))[tid] = o;
}

// ---------------------------------------------------------------------------
// GEMM: C[M,N] = A[M,K](bf16) * Bt[N,K]^T(bf16) + bias(fp32)
// TM = 128 or 64 (M-tile). N-tile fixed 128. BK=64, 4 waves (2x2).
// EPI: 1 = bias+relu -> bf16
//      2 = bias + fp32-res -> bf16 (residual stream)
//      5 = bias + bf16-res -> fp32 (final output)
// ---------------------------------------------------------------------------
template<int EPI, int TM>
__global__ __launch_bounds__(256) void gemm_bt(
    const u16* __restrict__ A, const u16* __restrict__ Bt,
    const float* __restrict__ bias, const void* __restrict__ res,
    void* __restrict__ Cv, int M, int N, int K, int lda, int ldb, int ldc) {
  constexpr int MI = TM / 32;           // acc rows per wave (4 or 2)
  constexpr int CA = TM / 32;           // A staging passes (4 or 2)
  __shared__ u16 As[TM * 64];
  __shared__ u16 Bs[128 * 64];
  const int bn = blockIdx.x, bm = blockIdx.y;
  const int m0 = bm * TM, n0 = bn * 128;
  const int tid = threadIdx.x;
  const int w = tid >> 6, l = tid & 63;
  const int lr = l & 15, lg = l >> 4;
  const int wr = w >> 1, wc = w & 1;

  f32x4 acc[MI][4] = {};

  for (int k0 = 0; k0 < K; k0 += 64) {
#pragma unroll
    for (int c = 0; c < 4; c++) {
      const int o = c * 4096 + tid * 16;               // linear LDS byte offset
      const int row = o >> 7;
      const int cb = o & 127;
      if (c < CA)
        GLOAD16((const char*)A + ((size_t)(m0 + row) * lda + k0) * 2 + cb,
                (char*)As + c * 4096 + w * 1024);
      GLOAD16((const char*)Bt + ((size_t)(n0 + row) * ldb + k0) * 2 + cb,
              (char*)Bs + c * 4096 + w * 1024);
    }
    __syncthreads();
#pragma unroll
    for (int kk = 0; kk < 2; kk++) {
      const int kb = kk * 64 + lg * 16;                // byte col within row
      s16x8 a[MI], b[4];
      for (int mi = 0; mi < MI; mi++) {
        int row = wr * (MI * 16) + mi * 16 + lr;
        a[mi] = *(const s16x8*)((const char*)As + ((row << 7) | kb));
      }
      for (int ni = 0; ni < 4; ni++) {
        int row = wc * 64 + ni * 16 + lr;
        b[ni] = *(const s16x8*)((const char*)Bs + ((row << 7) | kb));
      }
      for (int mi = 0; mi < MI; mi++)
        for (int ni = 0; ni < 4; ni++)
          acc[mi][ni] = __builtin_amdgcn_mfma_f32_16x16x32_bf16(
              a[mi], b[ni], acc[mi][ni], 0, 0, 0);
    }
    __syncthreads();
  }

  for (int mi = 0; mi < MI; mi++) {
    for (int ni = 0; ni < 4; ni++) {
      const int n = n0 + wc * 64 + ni * 16 + lr;
      const float bv = bias[n];
      for (int r = 0; r < 4; r++) {
        const int m = m0 + wr * (MI * 16) + mi * 16 + lg * 4 + r;
        float v = acc[mi][ni][r] + bv;
        if (EPI == 1) {
          v = v > 0.f ? v : 0.f;
          ((u16*)Cv)[(size_t)m * ldc + n] = f2bf(v);
        } else if (EPI == 2) {
          v += ((const float*)res)[(size_t)m * ldc + n];
          ((u16*)Cv)[(size_t)m * ldc + n] = f2bf(v);
        } else {  // EPI == 5
          v += bf2f(((const u16*)res)[(size_t)m * ldc + n]);
          ((float*)Cv)[(size_t)m * ldc + n] = v;
        }
      }
    }
  }
}

// ---------------------------------------------------------------------------
// Fused QKV GEMM: A[4096,1024] x WT[3072,1024]^T; seg 0->qbuf, 1->kbuf,
// 2->vT (transposed [B][dk+h*64][S]). 768 blocks = 3/CU.
// ---------------------------------------------------------------------------
__global__ __launch_bounds__(256) void gemm_qkv(
    const u16* __restrict__ A, const u16* __restrict__ WT,
    const float* __restrict__ bq, const float* __restrict__ bk,
    const float* __restrict__ bv,
    u16* __restrict__ qb_, u16* __restrict__ kb_, u16* __restrict__ vT_) {
  __shared__ u16 As[128 * 64];
  __shared__ u16 Bs[128 * 64];
  const int bn = blockIdx.x, bm = blockIdx.y;
  const int m0 = bm * 128, n0 = bn * 128;
  const int tid = threadIdx.x;
  const int w = tid >> 6, l = tid & 63;
  const int lr = l & 15, lg = l >> 4;
  const int wr = w >> 1, wc = w & 1;

  f32x4 acc[4][4] = {};

  for (int k0 = 0; k0 < 1024; k0 += 64) {
#pragma unroll
    for (int c = 0; c < 4; c++) {
      const int o = c * 4096 + tid * 16;
      const int row = o >> 7;
      const int cb = o & 127;
      GLOAD16((const char*)A + ((size_t)(m0 + row) * 1024 + k0) * 2 + cb,
              (char*)As + c * 4096 + w * 1024);
      GLOAD16((const char*)WT + ((size_t)(n0 + row) * 1024 + k0) * 2 + cb,
              (char*)Bs + c * 4096 + w * 1024);
    }
    __syncthreads();
#pragma unroll
    for (int kk = 0; kk < 2; kk++) {
      const int kb = kk * 64 + lg * 16;
      s16x8 a[4], b[4];
      for (int mi = 0; mi < 4; mi++) {
        int row = wr * 64 + mi * 16 + lr;
        a[mi] = *(const s16x8*)((const char*)As + ((row << 7) | kb));
      }
      for (int ni = 0; ni < 4; ni++) {
        int row = wc * 64 + ni * 16 + lr;
        b[ni] = *(const s16x8*)((const char*)Bs + ((row << 7) | kb));
      }
      for (int mi = 0; mi < 4; mi++)
        for (int ni = 0; ni < 4; ni++)
          acc[mi][ni] = __builtin_amdgcn_mfma_f32_16x16x32_bf16(
              a[mi], b[ni], acc[mi][ni], 0, 0, 0);
    }
    __syncthreads();
  }

  const int seg = n0 >> 10;                    // uniform per block
  for (int mi = 0; mi < 4; mi++) {
    for (int ni = 0; ni < 4; ni++) {
      const int n = n0 + wc * 64 + ni * 16 + lr;
      const int nn = n & 1023;
      const float bias = seg == 0 ? bq[nn] : seg == 1 ? bk[nn] : bv[nn];
      for (int r = 0; r < 4; r++) {
        const int m = m0 + wr * 64 + mi * 16 + lg * 4 + r;
        const u16 ov = f2bf(acc[mi][ni][r] + bias);
        if (seg == 0)      qb_[(size_t)m * 1024 + nn] = ov;
        else if (seg == 1) kb_[(size_t)m * 1024 + nn] = ov;
        else               vT_[(((size_t)(m >> 10)) * 1024 + nn) * 1024 + (m & 1023)] = ov;
      }
    }
  }
}

// ---------------------------------------------------------------------------
// Flash attention, LDS-staged KV (double-buffered, XOR-swizzled) + setprio.
// block = (qt 0..15, bh 0..63): 64 q-rows (4 waves x 16); KVBLK=64.
// ---------------------------------------------------------------------------
__global__ __launch_bounds__(256) void attn_kernel(
    const u16* __restrict__ q, const u16* __restrict__ k,
    const u16* __restrict__ vT, const int* __restrict__ mask,
    u16* __restrict__ ctx) {
  __shared__ u16 Ks[2][64 * 64];   // [kv][d] rows 128B, XOR-swizzled
  __shared__ u16 Vs[2][64 * 64];   // [d][kv] rows 128B, XOR-swizzled
  __shared__ u16 Pl[4][16][72];    // per-wave P tile (144B rows)
  const int qt = blockIdx.x;          // 0..15
  const int bh = blockIdx.y;          // 0..63
  const int b = bh >> 4, h = bh & 15;
  const int tid = threadIdx.x;
  const int w = tid >> 6, l = tid & 63;
  const int lr = l & 15, lg = l >> 4;
  const int qrow0 = qt * 64 + w * 16;

  const u16* qp = q + ((size_t)(b * 1024 + qrow0 + lr)) * 1024 + h * 64 + lg * 8;
  const s16x8 aq0 = *(const s16x8*)qp;
  const s16x8 aq1 = *(const s16x8*)(qp + 32);

  float mrow[4], lrow[4];
  f32x4 acc[4] = {};
  for (int r = 0; r < 4; r++) { mrow[r] = -1e30f; lrow[r] = 0.f; }

  const char* kby = (const char*)(k + ((size_t)(b * 1024)) * 1024 + h * 64);
  const char* vby = (const char*)(vT + ((size_t)b) * 1024 * 1024 + ((size_t)(h * 64)) * 1024);
  const int* mbase = mask + b * 1024;

  const int o0 = tid * 16;
#define STAGE_KV(bufi, t0_)                                                     \
  {                                                                             \
    _Pragma("unroll")                                                           \
    for (int c = 0; c < 2; c++) {                                               \
      const int o = c * 4096 + o0;                                              \
      const int row = o >> 7;                                                   \
      const int cb = (o & 127) ^ ((row & 7) << 4);                              \
      GLOAD16(kby + (size_t)(t0_ + row) * 2048 + cb,                            \
              (char*)Ks + (bufi) * 8192 + c * 4096 + w * 1024);                 \
      GLOAD16(vby + (size_t)row * 2048 + (size_t)(t0_) * 2 + cb,                \
              (char*)Vs + (bufi) * 8192 + c * 4096 + w * 1024);                 \
    }                                                                           \
  }

  STAGE_KV(0, 0);
  __syncthreads();

  int buf = 0;
  for (int it = 0; it < 16; ++it) {
    const int t0 = it * 64;
    if (it < 15) STAGE_KV(buf ^ 1, t0 + 64);

    // ---- QK^T over 64 kv rows (4 subs of 16) ----
    float p[4][4];
#pragma unroll
    for (int sub = 0; sub < 4; sub++) {
      const int krow = sub * 16 + lr;
      const int sw = (krow & 7) << 4;
      const char* kp = (const char*)Ks + buf * 8192 + (krow << 7);
      s16x8 bk0 = *(const s16x8*)(kp + ((lg * 16) ^ sw));
      s16x8 bk1 = *(const s16x8*)(kp + ((lg * 16 + 64) ^ sw));
      f32x4 d = {};
      __builtin_amdgcn_s_setprio(1);
      d = __builtin_amdgcn_mfma_f32_16x16x32_bf16(aq0, bk0, d, 0, 0, 0);
      d = __builtin_amdgcn_mfma_f32_16x16x32_bf16(aq1, bk1, d, 0, 0, 0);
      __builtin_amdgcn_s_setprio(0);
      const int mv = mbase[t0 + krow];
      for (int r = 0; r < 4; r++) {
        float s = d[r] * 0.125f;
        p[sub][r] = (mv == 0) ? -1e9f : s;
      }
    }
    // ---- online softmax ----
    float tmax[4];
    for (int r = 0; r < 4; r++)
      tmax[r] = fmaxf(fmaxf(p[0][r], p[1][r]), fmaxf(p[2][r], p[3][r]));
    for (int off = 1; off < 16; off <<= 1)
      for (int r = 0; r < 4; r++) tmax[r] = fmaxf(tmax[r], __shfl_xor(tmax[r], off, 64));
    float scl[4];
    for (int r = 0; r < 4; r++) {
      float mn = fmaxf(mrow[r], tmax[r]);
      scl[r] = __expf(mrow[r] - mn);
      mrow[r] = mn;
    }
    float ps[4];
    for (int r = 0; r < 4; r++) {
      ps[r] = 0.f;
      for (int sub = 0; sub < 4; sub++) {
        p[sub][r] = __expf(p[sub][r] - mrow[r]);
        ps[r] += p[sub][r];
      }
    }
    for (int off = 1; off < 16; off <<= 1)
      for (int r = 0; r < 4; r++) ps[r] += __shfl_xor(ps[r], off, 64);
    for (int r = 0; r < 4; r++) lrow[r] = lrow[r] * scl[r] + ps[r];
    for (int d4 = 0; d4 < 4; d4++)
      for (int r = 0; r < 4; r++) acc[d4][r] *= scl[r];
    // ---- P -> per-wave LDS; wave-local fence (rule #18) ----
#pragma unroll
    for (int sub = 0; sub < 4; sub++)
      for (int r = 0; r < 4; r++)
        Pl[w][lg * 4 + r][sub * 16 + lr] = f2bf(p[sub][r]);
    asm volatile("s_waitcnt lgkmcnt(0)" ::: "memory");
    __builtin_amdgcn_sched_barrier(0);
    // ---- PV: acc[q][d] += P[q][kv] * V^T[d][kv] ----
    __builtin_amdgcn_s_setprio(1);
#pragma unroll
    for (int kb2 = 0; kb2 < 2; kb2++) {
      const s16x8 ap = *(const s16x8*)&Pl[w][lr][kb2 * 32 + lg * 8];
      for (int d4 = 0; d4 < 4; d4++) {
        const int vrow = d4 * 16 + lr;
        const char* vp = (const char*)Vs + buf * 8192 + (vrow << 7);
        s16x8 bvv = *(const s16x8*)(vp + ((kb2 * 64 + lg * 16) ^ ((vrow & 7) << 4)));
        acc[d4] = __builtin_amdgcn_mfma_f32_16x16x32_bf16(ap, bvv, acc[d4], 0, 0, 0);
      }
    }
    __builtin_amdgcn_s_setprio(0);
    __syncthreads();
    buf ^= 1;
  }

  for (int d4 = 0; d4 < 4; d4++)
    for (int r = 0; r < 4; r++) {
      const int row = b * 1024 + qrow0 + lg * 4 + r;
      ctx[(size_t)row * 1024 + h * 64 + d4 * 16 + lr] = f2bf(acc[d4][r] / lrow[r]);
    }
#undef STAGE_KV
}

// ---------------------------------------------------------------------------
// Workspace layout (64 MB; ws_size >= 64 MB proven round 2/3):
//  [ 0.. 6) wqT,wkT,wvT (fused [3072][1024]) -> w1T [0..8) after O-proj
//  [ 6.. 8) woT
//  [ 8..16) xn (ctx after QKV)               -> w2T after O-proj
//  [16..24) qbuf                             -> xn2 after attention
//  [24..32) kbuf   \
//  [32..40) vT      >- hbuf [24..56) 32MB after attention
//  [40..56) (free) /
//  [56..64) x1 (bf16)
// ---------------------------------------------------------------------------
extern "C" void kernel_launch(void* const* d_in, const int* in_sizes, int n_in,
                              void* d_out, int out_size, void* d_ws, size_t ws_size,
                              hipStream_t stream) {
  float* out = (float*)d_out;

  const size_t REQUIRED = (size_t)64 * 1024 * 1024;
  if (ws_size < REQUIRED) {
    fill_kernel<<<dim3((out_size + 255) / 256), 256, 0, stream>>>(out, out_size);
    return;
  }

  const float* x    = (const float*)d_in[0];
  const int*   mask = (const int*)d_in[1];
  const float* wq = (const float*)d_in[2];
  const float* bq = (const float*)d_in[3];
  const float* wk = (const float*)d_in[4];
  const float* bk = (const float*)d_in[5];
  const float* wv = (const float*)d_in[6];
  const float* bv = (const float*)d_in[7];
  const float* wo = (const float*)d_in[8];
  const float* bo = (const float*)d_in[9];
  const float* w1 = (const float*)d_in[10];
  const float* b1 = (const float*)d_in[11];
  const float* w2 = (const float*)d_in[12];
  const float* b2 = (const float*)d_in[13];
  const float* alpha1 = (const float*)d_in[14];
  const float* beta1  = (const float*)d_in[15];
  const float* alpha2 = (const float*)d_in[16];
  const float* beta2  = (const float*)d_in[17];

  char* W = (char*)d_ws;
  const size_t MB = 1024 * 1024;
  u16* wqT  = (u16*)(W + 0 * MB);
  u16* wkT  = (u16*)(W + 2 * MB);
  u16* wvT  = (u16*)(W + 4 * MB);
  u16* woT  = (u16*)(W + 6 * MB);
  u16* xn   = (u16*)(W + 8 * MB);
  u16* qbuf = (u16*)(W + 16 * MB);
  u16* kbuf = (u16*)(W + 24 * MB);
  u16* vT   = (u16*)(W + 32 * MB);
  u16* x1b  = (u16*)(W + 56 * MB);  // bf16 residual stream
  u16* ctx  = xn;                   // reuse after QKV GEMM
  u16* w1T  = (u16*)(W + 0 * MB);   // after O-proj
  u16* w2T  = (u16*)(W + 8 * MB);   // after O-proj
  u16* xn2  = (u16*)(W + 16 * MB);  // after attention
  u16* hbuf = (u16*)(W + 24 * MB);  // [24..56) 32MB after attention

  // fp32 -> bf16^T weight conversion
  convT_kernel<<<dim3(16 * 16), 256, 0, stream>>>(wq, wqT, 1024, 1024);
  convT_kernel<<<dim3(16 * 16), 256, 0, stream>>>(wk, wkT, 1024, 1024);
  convT_kernel<<<dim3(16 * 16), 256, 0, stream>>>(wv, wvT, 1024, 1024);
  convT_kernel<<<dim3(16 * 16), 256, 0, stream>>>(wo, woT, 1024, 1024);

  ln_kernel<<<dim3(4096), 256, 0, stream>>>(x, xn, alpha1, beta1);

  // fused QKV: WT = wqT|wkT|wvT contiguous [3072][1024]
  gemm_qkv<<<dim3(24, 32), 256, 0, stream>>>(xn, wqT, bq, bk, bv, qbuf, kbuf, vT);

  attn_kernel<<<dim3(16, 64), 256, 0, stream>>>(qbuf, kbuf, vT, mask, ctx);

  // O-proj + fp32 residual x -> bf16 x1 (TM=64: 512 blocks, 2/CU)
  gemm_bt<2, 64><<<dim3(8, 64), 256, 0, stream>>>(
      ctx, woT, bo, x, x1b, 4096, 1024, 1024, 1024, 1024, 1024);

  // FFN weights (regions freed above)
  convT_kernel<<<dim3(16 * 64), 256, 0, stream>>>(w1, w1T, 1024, 4096);
  convT_kernel<<<dim3(64 * 16), 256, 0, stream>>>(w2, w2T, 4096, 1024);

  ln_bf16_kernel<<<dim3(4096), 256, 0, stream>>>(x1b, xn2, alpha2, beta2);

  // FFN1 full width (TM=128: 1024 blocks, 4/CU)
  gemm_bt<1, 128><<<dim3(32, 32), 256, 0, stream>>>(
      xn2, w1T, b1, nullptr, hbuf, 4096, 4096, 1024, 1024, 1024, 4096);
  // FFN2 full K (TM=64: 512 blocks, 2/CU), bf16 residual x1 -> fp32 out
  gemm_bt<5, 64><<<dim3(8, 64), 256, 0, stream>>>(
      hbuf, w2T, b2, x1b, out, 4096, 1024, 4096, 4096, 4096, 1024);
}

// Round 9
// 310.537 us; speedup vs baseline: 1.3496x; 1.0470x over previous
//
#include <hip/hip_runtime.h>

using u16 = unsigned short;
using s16x8 = __attribute__((ext_vector_type(8))) short;
using f32x4 = __attribute__((ext_vector_type(4))) float;

__device__ __forceinline__ float bf2f(u16 u) {
  union { unsigned int i; float f; } c; c.i = ((unsigned int)u) << 16; return c.f;
}
__device__ __forceinline__ u16 f2bf(float f) {
  union { float f; unsigned int i; } c; c.f = f;
  unsigned int x = c.i;
  return (u16)((x + 0x7fffu + ((x >> 16) & 1u)) >> 16);
}

#define GLOAD16(g, l) __builtin_amdgcn_global_load_lds(                         \
    (const __attribute__((address_space(1))) void*)(g),                          \
    (__attribute__((address_space(3))) void*)(l), 16, 0, 0)

// ---------------------------------------------------------------------------
__global__ __launch_bounds__(256) void fill_kernel(float* out, int n) {
  int i = blockIdx.x * 256 + threadIdx.x;
  if (i < n) out[i] = 999.0f;
}

// ---------------------------------------------------------------------------
// Fused convert+transpose: fp32 in[R][C] -> bf16 out[C][R]
// ---------------------------------------------------------------------------
__global__ __launch_bounds__(256) void convT_kernel(
    const float* __restrict__ in, u16* __restrict__ out, int R, int C) {
  __shared__ u16 t[64][72];
  const int nbc = C >> 6;
  const int br = blockIdx.x / nbc, bc = blockIdx.x % nbc;
  const int tid = threadIdx.x;
  const int r4 = tid >> 4;          // 0..15
  const int c4 = (tid & 15) * 4;    // 0..60
  for (int i = 0; i < 4; i++) {
    int row = i * 16 + r4;
    float4 v = *(const float4*)(in + (size_t)(br * 64 + row) * C + bc * 64 + c4);
    t[row][c4 + 0] = f2bf(v.x); t[row][c4 + 1] = f2bf(v.y);
    t[row][c4 + 2] = f2bf(v.z); t[row][c4 + 3] = f2bf(v.w);
  }
  __syncthreads();
  for (int i = 0; i < 4; i++) {
    int row2 = i * 16 + r4;         // C-index
    ushort4 v;
    v.x = t[c4 + 0][row2]; v.y = t[c4 + 1][row2];
    v.z = t[c4 + 2][row2]; v.w = t[c4 + 3][row2];
    *(ushort4*)(out + (size_t)(bc * 64 + row2) * R + br * 64 + c4) = v;
  }
}

// ---------------------------------------------------------------------------
// LayerNorm (unbiased var /1023, eps on std): fp32 or bf16 in -> bf16 out.
// ---------------------------------------------------------------------------
__global__ __launch_bounds__(256) void ln_kernel(
    const float* __restrict__ x, u16* __restrict__ y,
    const float* __restrict__ alpha, const float* __restrict__ beta) {
  __shared__ float red[8];
  const int row = blockIdx.x;
  const int tid = threadIdx.x;
  float4 u = ((const float4*)(x + (size_t)row * 1024))[tid];
  float v0 = u.x, v1 = u.y, v2 = u.z, v3 = u.w;
  float s = v0 + v1 + v2 + v3;
  for (int off = 32; off; off >>= 1) s += __shfl_xor(s, off, 64);
  if ((tid & 63) == 0) red[tid >> 6] = s;
  __syncthreads();
  float mean = (red[0] + red[1] + red[2] + red[3]) * (1.f / 1024.f);
  v0 -= mean; v1 -= mean; v2 -= mean; v3 -= mean;
  float q = v0 * v0 + v1 * v1 + v2 * v2 + v3 * v3;
  for (int off = 32; off; off >>= 1) q += __shfl_xor(q, off, 64);
  if ((tid & 63) == 0) red[4 + (tid >> 6)] = q;
  __syncthreads();
  float var = (red[4] + red[5] + red[6] + red[7]) * (1.f / 1023.f);
  float inv = 1.f / (sqrtf(var) + 1e-6f);
  float a = alpha[0], b = beta[0];
  ushort4 o;
  o.x = f2bf(a * v0 * inv + b); o.y = f2bf(a * v1 * inv + b);
  o.z = f2bf(a * v2 * inv + b); o.w = f2bf(a * v3 * inv + b);
  ((ushort4*)(y + (size_t)row * 1024))[tid] = o;
}

__global__ __launch_bounds__(256) void ln_bf16_kernel(
    const u16* __restrict__ x, u16* __restrict__ y,
    const float* __restrict__ alpha, const float* __restrict__ beta) {
  __shared__ float red[8];
  const int row = blockIdx.x;
  const int tid = threadIdx.x;
  ushort4 u = ((const ushort4*)(x + (size_t)row * 1024))[tid];
  float v0 = bf2f(u.x), v1 = bf2f(u.y), v2 = bf2f(u.z), v3 = bf2f(u.w);
  float s = v0 + v1 + v2 + v3;
  for (int off = 32; off; off >>= 1) s += __shfl_xor(s, off, 64);
  if ((tid & 63) == 0) red[tid >> 6] = s;
  __syncthreads();
  float mean = (red[0] + red[1] + red[2] + red[3]) * (1.f / 1024.f);
  v0 -= mean; v1 -= mean; v2 -= mean; v3 -= mean;
  float q = v0 * v0 + v1 * v1 + v2 * v2 + v3 * v3;
  for (int off = 32; off; off >>= 1) q += __shfl_xor(q, off, 64);
  if ((tid & 63) == 0) red[4 + (tid >> 6)] = q;
  __syncthreads();
  float var = (red[4] + red[5] + red[6] + red[7]) * (1.f / 1023.f);
  float inv = 1.f / (sqrtf(var) + 1e-6f);
  float a = alpha[0], b = beta[0];
  ushort4 o;
  o.x = f2bf(a * v0 * inv + b); o.y = f2bf(a * v1 * inv + b);
  o.z = f2bf(a * v2 * inv + b); o.w = f2bf(a * v3 * inv + b);
  ((ushort4*)(y + (size_t)row * 1024))[tid] = o;
}

// ---------------------------------------------------------------------------
// GEMM: C[M,N] = A[M,K](bf16) * Bt[N,K]^T(bf16) + bias(fp32)
// TM = 128 or 64 (M-tile). N-tile fixed 128. BK=64, 4 waves (2x2).
// EPI: 1 = bias+relu -> bf16
//      2 = bias + fp32-res -> bf16 (residual stream)
//      5 = bias + bf16-res -> fp32 (final output)
// ---------------------------------------------------------------------------
template<int EPI, int TM>
__global__ __launch_bounds__(256) void gemm_bt(
    const u16* __restrict__ A, const u16* __restrict__ Bt,
    const float* __restrict__ bias, const void* __restrict__ res,
    void* __restrict__ Cv, int M, int N, int K, int lda, int ldb, int ldc) {
  constexpr int MI = TM / 32;           // acc rows per wave (4 or 2)
  constexpr int CA = TM / 32;           // A staging passes (4 or 2)
  __shared__ u16 As[TM * 64];
  __shared__ u16 Bs[128 * 64];
  const int bn = blockIdx.x, bm = blockIdx.y;
  const int m0 = bm * TM, n0 = bn * 128;
  const int tid = threadIdx.x;
  const int w = tid >> 6, l = tid & 63;
  const int lr = l & 15, lg = l >> 4;
  const int wr = w >> 1, wc = w & 1;

  f32x4 acc[MI][4] = {};

  for (int k0 = 0; k0 < K; k0 += 64) {
#pragma unroll
    for (int c = 0; c < 4; c++) {
      const int o = c * 4096 + tid * 16;               // linear LDS byte offset
      const int row = o >> 7;
      const int cb = o & 127;
      if (c < CA)
        GLOAD16((const char*)A + ((size_t)(m0 + row) * lda + k0) * 2 + cb,
                (char*)As + c * 4096 + w * 1024);
      GLOAD16((const char*)Bt + ((size_t)(n0 + row) * ldb + k0) * 2 + cb,
              (char*)Bs + c * 4096 + w * 1024);
    }
    __syncthreads();
#pragma unroll
    for (int kk = 0; kk < 2; kk++) {
      const int kb = kk * 64 + lg * 16;                // byte col within row
      s16x8 a[MI], b[4];
      for (int mi = 0; mi < MI; mi++) {
        int row = wr * (MI * 16) + mi * 16 + lr;
        a[mi] = *(const s16x8*)((const char*)As + ((row << 7) | kb));
      }
      for (int ni = 0; ni < 4; ni++) {
        int row = wc * 64 + ni * 16 + lr;
        b[ni] = *(const s16x8*)((const char*)Bs + ((row << 7) | kb));
      }
      for (int mi = 0; mi < MI; mi++)
        for (int ni = 0; ni < 4; ni++)
          acc[mi][ni] = __builtin_amdgcn_mfma_f32_16x16x32_bf16(
              a[mi], b[ni], acc[mi][ni], 0, 0, 0);
    }
    __syncthreads();
  }

  for (int mi = 0; mi < MI; mi++) {
    for (int ni = 0; ni < 4; ni++) {
      const int n = n0 + wc * 64 + ni * 16 + lr;
      const float bv = bias[n];
      for (int r = 0; r < 4; r++) {
        const int m = m0 + wr * (MI * 16) + mi * 16 + lg * 4 + r;
        float v = acc[mi][ni][r] + bv;
        if (EPI == 1) {
          v = v > 0.f ? v : 0.f;
          ((u16*)Cv)[(size_t)m * ldc + n] = f2bf(v);
        } else if (EPI == 2) {
          v += ((const float*)res)[(size_t)m * ldc + n];
          ((u16*)Cv)[(size_t)m * ldc + n] = f2bf(v);
        } else {  // EPI == 5
          v += bf2f(((const u16*)res)[(size_t)m * ldc + n]);
          ((float*)Cv)[(size_t)m * ldc + n] = v;
        }
      }
    }
  }
}

// ---------------------------------------------------------------------------
// Fused QKV GEMM: A[4096,1024] x WT[3072,1024]^T; seg 0->qbuf, 1->kbuf,
// 2->vT (transposed [B][dk+h*64][S]). 768 blocks = 3/CU.
// ---------------------------------------------------------------------------
__global__ __launch_bounds__(256) void gemm_qkv(
    const u16* __restrict__ A, const u16* __restrict__ WT,
    const float* __restrict__ bq, const float* __restrict__ bk,
    const float* __restrict__ bv,
    u16* __restrict__ qb_, u16* __restrict__ kb_, u16* __restrict__ vT_) {
  __shared__ u16 As[128 * 64];
  __shared__ u16 Bs[128 * 64];
  const int bn = blockIdx.x, bm = blockIdx.y;
  const int m0 = bm * 128, n0 = bn * 128;
  const int tid = threadIdx.x;
  const int w = tid >> 6, l = tid & 63;
  const int lr = l & 15, lg = l >> 4;
  const int wr = w >> 1, wc = w & 1;

  f32x4 acc[4][4] = {};

  for (int k0 = 0; k0 < 1024; k0 += 64) {
#pragma unroll
    for (int c = 0; c < 4; c++) {
      const int o = c * 4096 + tid * 16;
      const int row = o >> 7;
      const int cb = o & 127;
      GLOAD16((const char*)A + ((size_t)(m0 + row) * 1024 + k0) * 2 + cb,
              (char*)As + c * 4096 + w * 1024);
      GLOAD16((const char*)WT + ((size_t)(n0 + row) * 1024 + k0) * 2 + cb,
              (char*)Bs + c * 4096 + w * 1024);
    }
    __syncthreads();
#pragma unroll
    for (int kk = 0; kk < 2; kk++) {
      const int kb = kk * 64 + lg * 16;
      s16x8 a[4], b[4];
      for (int mi = 0; mi < 4; mi++) {
        int row = wr * 64 + mi * 16 + lr;
        a[mi] = *(const s16x8*)((const char*)As + ((row << 7) | kb));
      }
      for (int ni = 0; ni < 4; ni++) {
        int row = wc * 64 + ni * 16 + lr;
        b[ni] = *(const s16x8*)((const char*)Bs + ((row << 7) | kb));
      }
      for (int mi = 0; mi < 4; mi++)
        for (int ni = 0; ni < 4; ni++)
          acc[mi][ni] = __builtin_amdgcn_mfma_f32_16x16x32_bf16(
              a[mi], b[ni], acc[mi][ni], 0, 0, 0);
    }
    __syncthreads();
  }

  const int seg = n0 >> 10;                    // uniform per block
  for (int mi = 0; mi < 4; mi++) {
    for (int ni = 0; ni < 4; ni++) {
      const int n = n0 + wc * 64 + ni * 16 + lr;
      const int nn = n & 1023;
      const float bias = seg == 0 ? bq[nn] : seg == 1 ? bk[nn] : bv[nn];
      for (int r = 0; r < 4; r++) {
        const int m = m0 + wr * 64 + mi * 16 + lg * 4 + r;
        const u16 ov = f2bf(acc[mi][ni][r] + bias);
        if (seg == 0)      qb_[(size_t)m * 1024 + nn] = ov;
        else if (seg == 1) kb_[(size_t)m * 1024 + nn] = ov;
        else               vT_[(((size_t)(m >> 10)) * 1024 + nn) * 1024 + (m & 1023)] = ov;
      }
    }
  }
}

// ---------------------------------------------------------------------------
// Flash attention, LDS-staged KV (SINGLE-buffered, XOR-swizzled).
// LDS 21 KB -> ~7 blocks/CU: latency chains hidden by TLP, not dbuf.
// block = (qt 0..15, bh 0..63): 64 q-rows (4 waves x 16); KVBLK=64.
// ---------------------------------------------------------------------------
__global__ __launch_bounds__(256) void attn_kernel(
    const u16* __restrict__ q, const u16* __restrict__ k,
    const u16* __restrict__ vT, const int* __restrict__ mask,
    u16* __restrict__ ctx) {
  __shared__ u16 Ks[64 * 64];      // [kv][d] rows 128B, XOR-swizzled
  __shared__ u16 Vs[64 * 64];      // [d][kv] rows 128B, XOR-swizzled
  __shared__ u16 Pl[4][16][72];    // per-wave P tile (144B rows)
  const int qt = blockIdx.x;          // 0..15
  const int bh = blockIdx.y;          // 0..63
  const int b = bh >> 4, h = bh & 15;
  const int tid = threadIdx.x;
  const int w = tid >> 6, l = tid & 63;
  const int lr = l & 15, lg = l >> 4;
  const int qrow0 = qt * 64 + w * 16;

  const u16* qp = q + ((size_t)(b * 1024 + qrow0 + lr)) * 1024 + h * 64 + lg * 8;
  const s16x8 aq0 = *(const s16x8*)qp;
  const s16x8 aq1 = *(const s16x8*)(qp + 32);

  float mrow[4], lrow[4];
  f32x4 acc[4] = {};
  for (int r = 0; r < 4; r++) { mrow[r] = -1e30f; lrow[r] = 0.f; }

  const char* kby = (const char*)(k + ((size_t)(b * 1024)) * 1024 + h * 64);
  const char* vby = (const char*)(vT + ((size_t)b) * 1024 * 1024 + ((size_t)(h * 64)) * 1024);
  const int* mbase = mask + b * 1024;

  const int o0 = tid * 16;
#define STAGE_KV(t0_)                                                           \
  {                                                                             \
    _Pragma("unroll")                                                           \
    for (int c = 0; c < 2; c++) {                                               \
      const int o = c * 4096 + o0;                                              \
      const int row = o >> 7;                                                   \
      const int cb = (o & 127) ^ ((row & 7) << 4);                              \
      GLOAD16(kby + (size_t)(t0_ + row) * 2048 + cb,                            \
              (char*)Ks + c * 4096 + w * 1024);                                 \
      GLOAD16(vby + (size_t)row * 2048 + (size_t)(t0_) * 2 + cb,                \
              (char*)Vs + c * 4096 + w * 1024);                                 \
    }                                                                           \
  }

  STAGE_KV(0);
  __syncthreads();

  for (int it = 0; it < 16; ++it) {
    const int t0 = it * 64;

    // ---- QK^T over 64 kv rows (4 subs of 16) ----
    float p[4][4];
#pragma unroll
    for (int sub = 0; sub < 4; sub++) {
      const int krow = sub * 16 + lr;
      const int sw = (krow & 7) << 4;
      const char* kp = (const char*)Ks + (krow << 7);
      s16x8 bk0 = *(const s16x8*)(kp + ((lg * 16) ^ sw));
      s16x8 bk1 = *(const s16x8*)(kp + ((lg * 16 + 64) ^ sw));
      f32x4 d = {};
      d = __builtin_amdgcn_mfma_f32_16x16x32_bf16(aq0, bk0, d, 0, 0, 0);
      d = __builtin_amdgcn_mfma_f32_16x16x32_bf16(aq1, bk1, d, 0, 0, 0);
      const int mv = mbase[t0 + krow];
      for (int r = 0; r < 4; r++) {
        float s = d[r] * 0.125f;
        p[sub][r] = (mv == 0) ? -1e9f : s;
      }
    }
    // ---- online softmax ----
    float tmax[4];
    for (int r = 0; r < 4; r++)
      tmax[r] = fmaxf(fmaxf(p[0][r], p[1][r]), fmaxf(p[2][r], p[3][r]));
    for (int off = 1; off < 16; off <<= 1)
      for (int r = 0; r < 4; r++) tmax[r] = fmaxf(tmax[r], __shfl_xor(tmax[r], off, 64));
    float scl[4];
    for (int r = 0; r < 4; r++) {
      float mn = fmaxf(mrow[r], tmax[r]);
      scl[r] = __expf(mrow[r] - mn);
      mrow[r] = mn;
    }
    float ps[4];
    for (int r = 0; r < 4; r++) {
      ps[r] = 0.f;
      for (int sub = 0; sub < 4; sub++) {
        p[sub][r] = __expf(p[sub][r] - mrow[r]);
        ps[r] += p[sub][r];
      }
    }
    for (int off = 1; off < 16; off <<= 1)
      for (int r = 0; r < 4; r++) ps[r] += __shfl_xor(ps[r], off, 64);
    for (int r = 0; r < 4; r++) lrow[r] = lrow[r] * scl[r] + ps[r];
    for (int d4 = 0; d4 < 4; d4++)
      for (int r = 0; r < 4; r++) acc[d4][r] *= scl[r];
    // ---- P -> per-wave LDS; wave-local fence (rule #18) ----
#pragma unroll
    for (int sub = 0; sub < 4; sub++)
      for (int r = 0; r < 4; r++)
        Pl[w][lg * 4 + r][sub * 16 + lr] = f2bf(p[sub][r]);
    asm volatile("s_waitcnt lgkmcnt(0)" ::: "memory");
    __builtin_amdgcn_sched_barrier(0);
    // ---- PV: acc[q][d] += P[q][kv] * V^T[d][kv] ----
#pragma unroll
    for (int kb2 = 0; kb2 < 2; kb2++) {
      const s16x8 ap = *(const s16x8*)&Pl[w][lr][kb2 * 32 + lg * 8];
      for (int d4 = 0; d4 < 4; d4++) {
        const int vrow = d4 * 16 + lr;
        const char* vp = (const char*)Vs + (vrow << 7);
        s16x8 bvv = *(const s16x8*)(vp + ((kb2 * 64 + lg * 16) ^ ((vrow & 7) << 4)));
        acc[d4] = __builtin_amdgcn_mfma_f32_16x16x32_bf16(ap, bvv, acc[d4], 0, 0, 0);
      }
    }
    // restage for next iteration
    if (it < 15) {
      __syncthreads();               // all waves done reading Ks/Vs
      STAGE_KV(t0 + 64);
      __syncthreads();               // staging complete (vmcnt drain)
    }
  }

  for (int d4 = 0; d4 < 4; d4++)
    for (int r = 0; r < 4; r++) {
      const int row = b * 1024 + qrow0 + lg * 4 + r;
      ctx[(size_t)row * 1024 + h * 64 + d4 * 16 + lr] = f2bf(acc[d4][r] / lrow[r]);
    }
#undef STAGE_KV
}

// ---------------------------------------------------------------------------
// Workspace layout (64 MB; ws_size >= 64 MB proven round 2/3):
//  [ 0.. 6) wqT,wkT,wvT (fused [3072][1024]) -> w1T [0..8) after O-proj
//  [ 6.. 8) woT
//  [ 8..16) xn (ctx after QKV)               -> w2T after O-proj
//  [16..24) qbuf                             -> xn2 after attention
//  [24..32) kbuf   \
//  [32..40) vT      >- hbuf [24..56) 32MB after attention
//  [40..56) (free) /
//  [56..64) x1 (bf16)
// ---------------------------------------------------------------------------
extern "C" void kernel_launch(void* const* d_in, const int* in_sizes, int n_in,
                              void* d_out, int out_size, void* d_ws, size_t ws_size,
                              hipStream_t stream) {
  float* out = (float*)d_out;

  const size_t REQUIRED = (size_t)64 * 1024 * 1024;
  if (ws_size < REQUIRED) {
    fill_kernel<<<dim3((out_size + 255) / 256), 256, 0, stream>>>(out, out_size);
    return;
  }

  const float* x    = (const float*)d_in[0];
  const int*   mask = (const int*)d_in[1];
  const float* wq = (const float*)d_in[2];
  const float* bq = (const float*)d_in[3];
  const float* wk = (const float*)d_in[4];
  const float* bk = (const float*)d_in[5];
  const float* wv = (const float*)d_in[6];
  const float* bv = (const float*)d_in[7];
  const float* wo = (const float*)d_in[8];
  const float* bo = (const float*)d_in[9];
  const float* w1 = (const float*)d_in[10];
  const float* b1 = (const float*)d_in[11];
  const float* w2 = (const float*)d_in[12];
  const float* b2 = (const float*)d_in[13];
  const float* alpha1 = (const float*)d_in[14];
  const float* beta1  = (const float*)d_in[15];
  const float* alpha2 = (const float*)d_in[16];
  const float* beta2  = (const float*)d_in[17];

  char* W = (char*)d_ws;
  const size_t MB = 1024 * 1024;
  u16* wqT  = (u16*)(W + 0 * MB);
  u16* wkT  = (u16*)(W + 2 * MB);
  u16* wvT  = (u16*)(W + 4 * MB);
  u16* woT  = (u16*)(W + 6 * MB);
  u16* xn   = (u16*)(W + 8 * MB);
  u16* qbuf = (u16*)(W + 16 * MB);
  u16* kbuf = (u16*)(W + 24 * MB);
  u16* vT   = (u16*)(W + 32 * MB);
  u16* x1b  = (u16*)(W + 56 * MB);  // bf16 residual stream
  u16* ctx  = xn;                   // reuse after QKV GEMM
  u16* w1T  = (u16*)(W + 0 * MB);   // after O-proj
  u16* w2T  = (u16*)(W + 8 * MB);   // after O-proj
  u16* xn2  = (u16*)(W + 16 * MB);  // after attention
  u16* hbuf = (u16*)(W + 24 * MB);  // [24..56) 32MB after attention

  // fp32 -> bf16^T weight conversion
  convT_kernel<<<dim3(16 * 16), 256, 0, stream>>>(wq, wqT, 1024, 1024);
  convT_kernel<<<dim3(16 * 16), 256, 0, stream>>>(wk, wkT, 1024, 1024);
  convT_kernel<<<dim3(16 * 16), 256, 0, stream>>>(wv, wvT, 1024, 1024);
  convT_kernel<<<dim3(16 * 16), 256, 0, stream>>>(wo, woT, 1024, 1024);

  ln_kernel<<<dim3(4096), 256, 0, stream>>>(x, xn, alpha1, beta1);

  // fused QKV: WT = wqT|wkT|wvT contiguous [3072][1024]
  gemm_qkv<<<dim3(24, 32), 256, 0, stream>>>(xn, wqT, bq, bk, bv, qbuf, kbuf, vT);

  attn_kernel<<<dim3(16, 64), 256, 0, stream>>>(qbuf, kbuf, vT, mask, ctx);

  // O-proj + fp32 residual x -> bf16 x1 (TM=64: 512 blocks, 2/CU)
  gemm_bt<2, 64><<<dim3(8, 64), 256, 0, stream>>>(
      ctx, woT, bo, x, x1b, 4096, 1024, 1024, 1024, 1024, 1024);

  // FFN weights (regions freed above)
  convT_kernel<<<dim3(16 * 64), 256, 0, stream>>>(w1, w1T, 1024, 4096);
  convT_kernel<<<dim3(64 * 16), 256, 0, stream>>>(w2, w2T, 4096, 1024);

  ln_bf16_kernel<<<dim3(4096), 256, 0, stream>>>(x1b, xn2, alpha2, beta2);

  // FFN1 full width (TM=128: 1024 blocks, 4/CU)
  gemm_bt<1, 128><<<dim3(32, 32), 256, 0, stream>>>(
      xn2, w1T, b1, nullptr, hbuf, 4096, 4096, 1024, 1024, 1024, 4096);
  // FFN2 full K (TM=64: 512 blocks, 2/CU), bf16 residual x1 -> fp32 out
  gemm_bt<5, 64><<<dim3(8, 64), 256, 0, stream>>>(
      hbuf, w2T, b2, x1b, out, 4096, 1024, 4096, 4096, 4096, 1024);
}